// Round 1
// baseline (1405.065 us; speedup 1.0000x reference)
//
#include <hip/hip_runtime.h>

#define N_   8
#define C_   128
#define H_   96
#define W_   96
#define G_   8
#define GC_  16
#define HW_  (H_ * W_)       // 9216
#define CHW_ (C_ * HW_)      // 1179648
#define OM_  216
#define EPS_ 1e-5f

// ---------------------------------------------------------------------------
// K1: depthwise 3x3 conv + bias (NCHW -> NCHW) + per-sample sum/sumsq partials
// Grid: N*CHW/256 blocks of 256. Each block lies inside one (n,c) slice.
// ---------------------------------------------------------------------------
__global__ __launch_bounds__(256) void k_dwconv(const float* __restrict__ x,
                                                const float* __restrict__ dw_w,
                                                const float* __restrict__ dw_b,
                                                float* __restrict__ x1,
                                                float* __restrict__ stats) {
  int tid = threadIdx.x;
  int idx = blockIdx.x * 256 + tid;
  int n = idx / CHW_;
  int r = idx - n * CHW_;
  int c = r / HW_;
  int p = r - c * HW_;
  int h = p / W_;
  int w = p - h * W_;

  const float* wp = dw_w + c * 9;
  const float* xp = x + (n * C_ + c) * HW_;
  float acc = dw_b[c];
#pragma unroll
  for (int dy = 0; dy < 3; ++dy) {
#pragma unroll
    for (int dx = 0; dx < 3; ++dx) {
      int yy = h + dy - 1;
      int xx = w + dx - 1;
      bool v = (yy >= 0) & (yy < H_) & (xx >= 0) & (xx < W_);
      float xin = v ? xp[yy * W_ + xx] : 0.0f;
      acc = fmaf(xin, wp[dy * 3 + dx], acc);
    }
  }
  x1[idx] = acc;

  // block reduction of sum / sumsq (n is uniform within the block)
  float s = acc;
  float q = acc * acc;
#pragma unroll
  for (int o = 32; o > 0; o >>= 1) {
    s += __shfl_down(s, o);
    q += __shfl_down(q, o);
  }
  __shared__ float ls[4], lq[4];
  int lane = tid & 63;
  int wv = tid >> 6;
  if (lane == 0) { ls[wv] = s; lq[wv] = q; }
  __syncthreads();
  if (tid == 0) {
    float ts = ls[0] + ls[1] + ls[2] + ls[3];
    float tq = lq[0] + lq[1] + lq[2] + lq[3];
    atomicAdd(&stats[n * 2 + 0], ts);
    atomicAdd(&stats[n * 2 + 1], tq);
  }
}

// ---------------------------------------------------------------------------
// K2: transpose x NCHW -> NHWC (xv), 32x32 LDS tiles over (c, p)
// Grid: (HW/32=288, C/32=4, N=8), block (32,8)
// ---------------------------------------------------------------------------
__global__ __launch_bounds__(256) void k_transpose(const float* __restrict__ x,
                                                   float* __restrict__ xv) {
  __shared__ float tile[32][33];
  int tx = threadIdx.x;
  int ty = threadIdx.y;
  int p0 = blockIdx.x * 32;
  int c0 = blockIdx.y * 32;
  int n = blockIdx.z;
#pragma unroll
  for (int i = 0; i < 4; ++i) {
    int c = c0 + ty + i * 8;
    tile[ty + i * 8][tx] = x[(n * C_ + c) * HW_ + p0 + tx];
  }
  __syncthreads();
#pragma unroll
  for (int i = 0; i < 4; ++i) {
    int p = p0 + ty + i * 8;
    xv[(n * HW_ + p) * C_ + c0 + tx] = tile[tx][ty + i * 8];
  }
}

// ---------------------------------------------------------------------------
// K3: per-sample layernorm + affine + exact GELU, in-place on x1
// ---------------------------------------------------------------------------
__global__ __launch_bounds__(256) void k_norm_gelu(float* __restrict__ x1,
                                                   const float* __restrict__ stats,
                                                   const float* __restrict__ gn_w,
                                                   const float* __restrict__ gn_b) {
  int idx = blockIdx.x * 256 + threadIdx.x;
  int n = idx / CHW_;
  int c = (idx - n * CHW_) / HW_;
  float s = stats[n * 2 + 0];
  float q = stats[n * 2 + 1];
  const float inv = 1.0f / (float)CHW_;
  float mean = s * inv;
  float var = q * inv - mean * mean;
  float rstd = rsqrtf(var + EPS_);
  float v = (x1[idx] - mean) * rstd * gn_w[c] + gn_b[c];
  float g = 0.5f * v * (1.0f + erff(v * 0.70710678118654752f));
  x1[idx] = g;
}

// ---------------------------------------------------------------------------
// K4: om[n,o,p] = sum_c om_w[o,c] * x1n[n,c,p] + om_b[o]
// Block: 256 threads = 2 row-halves x 128 cols. Tile: 54 rows x 128 cols.
// A (54x128) staged fully in LDS; broadcast reads (wave-uniform address).
// Grid: (HW/128=72, 216/54=4, N=8)
// ---------------------------------------------------------------------------
__global__ __launch_bounds__(256) void k_gemm(const float* __restrict__ B,
                                              const float* __restrict__ Aw,
                                              const float* __restrict__ bias,
                                              float* __restrict__ Cm) {
  __shared__ float As[54 * 128];
  int tid = threadIdx.x;
  int ct = blockIdx.x;
  int rt = blockIdx.y;
  int n = blockIdx.z;
  int r0 = rt * 54;

  for (int i = tid; i < 54 * 128; i += 256) As[i] = Aw[r0 * 128 + i];
  __syncthreads();

  int half = tid >> 7;                  // wave-uniform
  int col = (tid & 127) + ct * 128;
  int rbase = half * 27;

  const float* Bp = B + n * CHW_ + col; // B[c, col] = Bp[c*HW_]
  float acc[27];
#pragma unroll
  for (int r = 0; r < 27; ++r) acc[r] = bias[r0 + rbase + r];

  for (int c = 0; c < 128; c += 4) {
    float b0 = Bp[(c + 0) * HW_];
    float b1 = Bp[(c + 1) * HW_];
    float b2 = Bp[(c + 2) * HW_];
    float b3 = Bp[(c + 3) * HW_];
#pragma unroll
    for (int r = 0; r < 27; ++r) {
      const float4 a = *(const float4*)&As[(rbase + r) * 128 + c];
      acc[r] = fmaf(a.x, b0, acc[r]);
      acc[r] = fmaf(a.y, b1, acc[r]);
      acc[r] = fmaf(a.z, b2, acc[r]);
      acc[r] = fmaf(a.w, b3, acc[r]);
    }
  }

  float* Cp = Cm + (n * OM_ + r0 + rbase) * HW_ + col;
#pragma unroll
  for (int r = 0; r < 27; ++r) Cp[r * HW_] = acc[r];
}

// ---------------------------------------------------------------------------
// K5: deformable bilinear sampling.
// Thread = (n, g, p). 27 coalesced om loads, 9 pts x 4 corners x 4 float4.
// Grid: N*G*HW/256 = 2304 blocks.
// ---------------------------------------------------------------------------
__global__ __launch_bounds__(256) void k_sample(const float* __restrict__ xv,
                                                const float* __restrict__ om,
                                                float* __restrict__ out) {
  int tid = threadIdx.x;
  int t = blockIdx.x * 256 + tid;
  int p = t % HW_;
  int rg = t / HW_;
  int g = rg % G_;
  int n = rg / G_;
  int h = p / W_;
  int w = p - h * W_;

  const float* omp = om + (n * OM_ + g * 27) * HW_ + p;
  float v[27];
#pragma unroll
  for (int j = 0; j < 27; ++j) v[j] = omp[j * HW_];

  float4 a0 = {0, 0, 0, 0}, a1 = {0, 0, 0, 0}, a2 = {0, 0, 0, 0}, a3 = {0, 0, 0, 0};
  const float* xb = xv + n * HW_ * C_ + g * GC_;

#pragma unroll
  for (int k = 0; k < 9; ++k) {
    float offx = v[2 * k + 0];
    float offy = v[2 * k + 1];
    float m = v[18 + k];
    float locy = (float)(h + k / 3 - 1) + offy;
    float locx = (float)(w + k % 3 - 1) + offx;
    float y0f = floorf(locy);
    float x0f = floorf(locx);
    float ly = locy - y0f;
    float lx = locx - x0f;
    int y0 = (int)y0f;
    int x0 = (int)x0f;
    float wts[4] = {(1.0f - ly) * (1.0f - lx) * m, (1.0f - ly) * lx * m,
                    ly * (1.0f - lx) * m, ly * lx * m};
#pragma unroll
    for (int cor = 0; cor < 4; ++cor) {
      int yy = y0 + (cor >> 1);
      int xx = x0 + (cor & 1);
      bool valid = (yy >= 0) & (yy < H_) & (xx >= 0) & (xx < W_);
      float wt = valid ? wts[cor] : 0.0f;
      int yc = min(max(yy, 0), H_ - 1);
      int xc = min(max(xx, 0), W_ - 1);
      const float4* src = (const float4*)(xb + (yc * W_ + xc) * C_);
      float4 s0 = src[0], s1 = src[1], s2 = src[2], s3 = src[3];
      a0.x = fmaf(wt, s0.x, a0.x); a0.y = fmaf(wt, s0.y, a0.y);
      a0.z = fmaf(wt, s0.z, a0.z); a0.w = fmaf(wt, s0.w, a0.w);
      a1.x = fmaf(wt, s1.x, a1.x); a1.y = fmaf(wt, s1.y, a1.y);
      a1.z = fmaf(wt, s1.z, a1.z); a1.w = fmaf(wt, s1.w, a1.w);
      a2.x = fmaf(wt, s2.x, a2.x); a2.y = fmaf(wt, s2.y, a2.y);
      a2.z = fmaf(wt, s2.z, a2.z); a2.w = fmaf(wt, s2.w, a2.w);
      a3.x = fmaf(wt, s3.x, a3.x); a3.y = fmaf(wt, s3.y, a3.y);
      a3.z = fmaf(wt, s3.z, a3.z); a3.w = fmaf(wt, s3.w, a3.w);
    }
  }

  float* op = out + (n * C_ + g * GC_) * HW_ + p;
  op[0 * HW_]  = a0.x; op[1 * HW_]  = a0.y; op[2 * HW_]  = a0.z; op[3 * HW_]  = a0.w;
  op[4 * HW_]  = a1.x; op[5 * HW_]  = a1.y; op[6 * HW_]  = a1.z; op[7 * HW_]  = a1.w;
  op[8 * HW_]  = a2.x; op[9 * HW_]  = a2.y; op[10 * HW_] = a2.z; op[11 * HW_] = a2.w;
  op[12 * HW_] = a3.x; op[13 * HW_] = a3.y; op[14 * HW_] = a3.z; op[15 * HW_] = a3.w;
}

// ---------------------------------------------------------------------------
extern "C" void kernel_launch(void* const* d_in, const int* in_sizes, int n_in,
                              void* d_out, int out_size, void* d_ws, size_t ws_size,
                              hipStream_t stream) {
  const float* x    = (const float*)d_in[0];
  const float* dw_w = (const float*)d_in[1];
  const float* dw_b = (const float*)d_in[2];
  const float* gn_w = (const float*)d_in[3];
  const float* gn_b = (const float*)d_in[4];
  const float* om_w = (const float*)d_in[5];
  const float* om_b = (const float*)d_in[6];
  float* out = (float*)d_out;

  float* ws = (float*)d_ws;
  float* x1 = ws;                        // N*C*H*W      = 9437184 floats
  float* xv = x1 + (size_t)N_ * CHW_;    // N*H*W*C      = 9437184 floats
  float* om = xv + (size_t)N_ * CHW_;    // N*216*HW     = 15925248 floats
  float* stats = om + (size_t)N_ * OM_ * HW_;  // 16 floats

  hipMemsetAsync(stats, 0, 16 * sizeof(float), stream);

  k_dwconv<<<(N_ * CHW_) / 256, 256, 0, stream>>>(x, dw_w, dw_b, x1, stats);
  k_transpose<<<dim3(HW_ / 32, C_ / 32, N_), dim3(32, 8), 0, stream>>>(x, xv);
  k_norm_gelu<<<(N_ * CHW_) / 256, 256, 0, stream>>>(x1, stats, gn_w, gn_b);
  k_gemm<<<dim3(HW_ / 128, OM_ / 54, N_), 256, 0, stream>>>(x1, om_w, om_b, om);
  k_sample<<<2304, 256, 0, stream>>>(xv, om, out);
}

// Round 2
// 494.638 us; speedup vs baseline: 2.8406x; 2.8406x over previous
//
#include <hip/hip_runtime.h>

#define N_   8
#define C_   128
#define H_   96
#define W_   96
#define G_   8
#define GC_  16
#define HW_  (H_ * W_)       // 9216
#define CHW_ (C_ * HW_)      // 1179648
#define OM_  216
#define EPS_ 1e-5f
#define BLKS_PER_N_ (CHW_ / 256)   // 4608

// ---------------------------------------------------------------------------
// K1: depthwise 3x3 conv + bias (NCHW -> NCHW) + per-BLOCK sum/sumsq partials
// (no atomics — partials reduced by k_stats). Blocks lie inside one (n,c).
// ---------------------------------------------------------------------------
__global__ __launch_bounds__(256) void k_dwconv(const float* __restrict__ x,
                                                const float* __restrict__ dw_w,
                                                const float* __restrict__ dw_b,
                                                float* __restrict__ x1,
                                                float2* __restrict__ partials) {
  int tid = threadIdx.x;
  int idx = blockIdx.x * 256 + tid;
  int n = idx / CHW_;
  int r = idx - n * CHW_;
  int c = r / HW_;
  int p = r - c * HW_;
  int h = p / W_;
  int w = p - h * W_;

  const float* wp = dw_w + c * 9;
  const float* xp = x + (n * C_ + c) * HW_;
  float acc = dw_b[c];
#pragma unroll
  for (int dy = 0; dy < 3; ++dy) {
#pragma unroll
    for (int dx = 0; dx < 3; ++dx) {
      int yy = h + dy - 1;
      int xx = w + dx - 1;
      bool v = (yy >= 0) & (yy < H_) & (xx >= 0) & (xx < W_);
      float xin = v ? xp[yy * W_ + xx] : 0.0f;
      acc = fmaf(xin, wp[dy * 3 + dx], acc);
    }
  }
  x1[idx] = acc;

  float s = acc;
  float q = acc * acc;
#pragma unroll
  for (int o = 32; o > 0; o >>= 1) {
    s += __shfl_down(s, o);
    q += __shfl_down(q, o);
  }
  __shared__ float ls[4], lq[4];
  int lane = tid & 63;
  int wv = tid >> 6;
  if (lane == 0) { ls[wv] = s; lq[wv] = q; }
  __syncthreads();
  if (tid == 0) {
    float ts = ls[0] + ls[1] + ls[2] + ls[3];
    float tq = lq[0] + lq[1] + lq[2] + lq[3];
    partials[blockIdx.x] = make_float2(ts, tq);
  }
}

// ---------------------------------------------------------------------------
// K1b: reduce 4608 per-block partials per sample -> stats[n] = (sum, sumsq)
// Grid: 8 blocks of 256.
// ---------------------------------------------------------------------------
__global__ __launch_bounds__(256) void k_stats(const float2* __restrict__ partials,
                                               float* __restrict__ stats) {
  int n = blockIdx.x;
  int tid = threadIdx.x;
  const float2* p = partials + n * BLKS_PER_N_;
  float s = 0.0f, q = 0.0f;
  for (int i = tid; i < BLKS_PER_N_; i += 256) {
    float2 v = p[i];
    s += v.x;
    q += v.y;
  }
#pragma unroll
  for (int o = 32; o > 0; o >>= 1) {
    s += __shfl_down(s, o);
    q += __shfl_down(q, o);
  }
  __shared__ float ls[4], lq[4];
  int lane = tid & 63;
  int wv = tid >> 6;
  if (lane == 0) { ls[wv] = s; lq[wv] = q; }
  __syncthreads();
  if (tid == 0) {
    stats[n * 2 + 0] = ls[0] + ls[1] + ls[2] + ls[3];
    stats[n * 2 + 1] = lq[0] + lq[1] + lq[2] + lq[3];
  }
}

// ---------------------------------------------------------------------------
// K2: transpose x NCHW -> NHWC (xv), 32x32 LDS tiles over (c, p)
// Grid: (HW/32=288, C/32=4, N=8), block (32,8)
// ---------------------------------------------------------------------------
__global__ __launch_bounds__(256) void k_transpose(const float* __restrict__ x,
                                                   float* __restrict__ xv) {
  __shared__ float tile[32][33];
  int tx = threadIdx.x;
  int ty = threadIdx.y;
  int p0 = blockIdx.x * 32;
  int c0 = blockIdx.y * 32;
  int n = blockIdx.z;
#pragma unroll
  for (int i = 0; i < 4; ++i) {
    int c = c0 + ty + i * 8;
    tile[ty + i * 8][tx] = x[(n * C_ + c) * HW_ + p0 + tx];
  }
  __syncthreads();
#pragma unroll
  for (int i = 0; i < 4; ++i) {
    int p = p0 + ty + i * 8;
    xv[(n * HW_ + p) * C_ + c0 + tx] = tile[tx][ty + i * 8];
  }
}

// ---------------------------------------------------------------------------
// K3: per-sample layernorm + affine + exact GELU, in-place on x1
// ---------------------------------------------------------------------------
__global__ __launch_bounds__(256) void k_norm_gelu(float* __restrict__ x1,
                                                   const float* __restrict__ stats,
                                                   const float* __restrict__ gn_w,
                                                   const float* __restrict__ gn_b) {
  int idx = blockIdx.x * 256 + threadIdx.x;
  int n = idx / CHW_;
  int c = (idx - n * CHW_) / HW_;
  float s = stats[n * 2 + 0];
  float q = stats[n * 2 + 1];
  const float inv = 1.0f / (float)CHW_;
  float mean = s * inv;
  float var = q * inv - mean * mean;
  float rstd = rsqrtf(var + EPS_);
  float v = (x1[idx] - mean) * rstd * gn_w[c] + gn_b[c];
  float g = 0.5f * v * (1.0f + erff(v * 0.70710678118654752f));
  x1[idx] = g;
}

// ---------------------------------------------------------------------------
// K4: om[n,o,p] = sum_c om_w[o,c] * x1n[n,c,p] + om_b[o]
// Block: 256 threads = 2 row-halves x 128 cols. Tile: 54 rows x 128 cols.
// A (54x128) staged fully in LDS; broadcast reads (wave-uniform address).
// Grid: (HW/128=72, 216/54=4, N=8)
// ---------------------------------------------------------------------------
__global__ __launch_bounds__(256) void k_gemm(const float* __restrict__ B,
                                              const float* __restrict__ Aw,
                                              const float* __restrict__ bias,
                                              float* __restrict__ Cm) {
  __shared__ float As[54 * 128];
  int tid = threadIdx.x;
  int ct = blockIdx.x;
  int rt = blockIdx.y;
  int n = blockIdx.z;
  int r0 = rt * 54;

  for (int i = tid; i < 54 * 128; i += 256) As[i] = Aw[r0 * 128 + i];
  __syncthreads();

  int half = tid >> 7;                  // wave-uniform
  int col = (tid & 127) + ct * 128;
  int rbase = half * 27;

  const float* Bp = B + n * CHW_ + col; // B[c, col] = Bp[c*HW_]
  float acc[27];
#pragma unroll
  for (int r = 0; r < 27; ++r) acc[r] = bias[r0 + rbase + r];

  for (int c = 0; c < 128; c += 4) {
    float b0 = Bp[(c + 0) * HW_];
    float b1 = Bp[(c + 1) * HW_];
    float b2 = Bp[(c + 2) * HW_];
    float b3 = Bp[(c + 3) * HW_];
#pragma unroll
    for (int r = 0; r < 27; ++r) {
      const float4 a = *(const float4*)&As[(rbase + r) * 128 + c];
      acc[r] = fmaf(a.x, b0, acc[r]);
      acc[r] = fmaf(a.y, b1, acc[r]);
      acc[r] = fmaf(a.z, b2, acc[r]);
      acc[r] = fmaf(a.w, b3, acc[r]);
    }
  }

  float* Cp = Cm + (n * OM_ + r0 + rbase) * HW_ + col;
#pragma unroll
  for (int r = 0; r < 27; ++r) Cp[r * HW_] = acc[r];
}

// ---------------------------------------------------------------------------
// K5: deformable bilinear sampling.
// Thread = (n, g, p). 27 coalesced om loads, 9 pts x 4 corners x 4 float4.
// Grid: N*G*HW/256 = 2304 blocks.
// ---------------------------------------------------------------------------
__global__ __launch_bounds__(256) void k_sample(const float* __restrict__ xv,
                                                const float* __restrict__ om,
                                                float* __restrict__ out) {
  int tid = threadIdx.x;
  int t = blockIdx.x * 256 + tid;
  int p = t % HW_;
  int rg = t / HW_;
  int g = rg % G_;
  int n = rg / G_;
  int h = p / W_;
  int w = p - h * W_;

  const float* omp = om + (n * OM_ + g * 27) * HW_ + p;
  float v[27];
#pragma unroll
  for (int j = 0; j < 27; ++j) v[j] = omp[j * HW_];

  float4 a0 = {0, 0, 0, 0}, a1 = {0, 0, 0, 0}, a2 = {0, 0, 0, 0}, a3 = {0, 0, 0, 0};
  const float* xb = xv + n * HW_ * C_ + g * GC_;

#pragma unroll
  for (int k = 0; k < 9; ++k) {
    float offx = v[2 * k + 0];
    float offy = v[2 * k + 1];
    float m = v[18 + k];
    float locy = (float)(h + k / 3 - 1) + offy;
    float locx = (float)(w + k % 3 - 1) + offx;
    float y0f = floorf(locy);
    float x0f = floorf(locx);
    float ly = locy - y0f;
    float lx = locx - x0f;
    int y0 = (int)y0f;
    int x0 = (int)x0f;
    float wts[4] = {(1.0f - ly) * (1.0f - lx) * m, (1.0f - ly) * lx * m,
                    ly * (1.0f - lx) * m, ly * lx * m};
#pragma unroll
    for (int cor = 0; cor < 4; ++cor) {
      int yy = y0 + (cor >> 1);
      int xx = x0 + (cor & 1);
      bool valid = (yy >= 0) & (yy < H_) & (xx >= 0) & (xx < W_);
      float wt = valid ? wts[cor] : 0.0f;
      int yc = min(max(yy, 0), H_ - 1);
      int xc = min(max(xx, 0), W_ - 1);
      const float4* src = (const float4*)(xb + (yc * W_ + xc) * C_);
      float4 s0 = src[0], s1 = src[1], s2 = src[2], s3 = src[3];
      a0.x = fmaf(wt, s0.x, a0.x); a0.y = fmaf(wt, s0.y, a0.y);
      a0.z = fmaf(wt, s0.z, a0.z); a0.w = fmaf(wt, s0.w, a0.w);
      a1.x = fmaf(wt, s1.x, a1.x); a1.y = fmaf(wt, s1.y, a1.y);
      a1.z = fmaf(wt, s1.z, a1.z); a1.w = fmaf(wt, s1.w, a1.w);
      a2.x = fmaf(wt, s2.x, a2.x); a2.y = fmaf(wt, s2.y, a2.y);
      a2.z = fmaf(wt, s2.z, a2.z); a2.w = fmaf(wt, s2.w, a2.w);
      a3.x = fmaf(wt, s3.x, a3.x); a3.y = fmaf(wt, s3.y, a3.y);
      a3.z = fmaf(wt, s3.z, a3.z); a3.w = fmaf(wt, s3.w, a3.w);
    }
  }

  float* op = out + (n * C_ + g * GC_) * HW_ + p;
  op[0 * HW_]  = a0.x; op[1 * HW_]  = a0.y; op[2 * HW_]  = a0.z; op[3 * HW_]  = a0.w;
  op[4 * HW_]  = a1.x; op[5 * HW_]  = a1.y; op[6 * HW_]  = a1.z; op[7 * HW_]  = a1.w;
  op[8 * HW_]  = a2.x; op[9 * HW_]  = a2.y; op[10 * HW_] = a2.z; op[11 * HW_] = a2.w;
  op[12 * HW_] = a3.x; op[13 * HW_] = a3.y; op[14 * HW_] = a3.z; op[15 * HW_] = a3.w;
}

// ---------------------------------------------------------------------------
extern "C" void kernel_launch(void* const* d_in, const int* in_sizes, int n_in,
                              void* d_out, int out_size, void* d_ws, size_t ws_size,
                              hipStream_t stream) {
  const float* x    = (const float*)d_in[0];
  const float* dw_w = (const float*)d_in[1];
  const float* dw_b = (const float*)d_in[2];
  const float* gn_w = (const float*)d_in[3];
  const float* gn_b = (const float*)d_in[4];
  const float* om_w = (const float*)d_in[5];
  const float* om_b = (const float*)d_in[6];
  float* out = (float*)d_out;

  float* ws = (float*)d_ws;
  float* x1 = ws;                        // N*C*H*W      = 9437184 floats
  float* xv = x1 + (size_t)N_ * CHW_;    // N*H*W*C      = 9437184 floats
  float* om = xv + (size_t)N_ * CHW_;    // N*216*HW     = 15925248 floats
  float* stats = om + (size_t)N_ * OM_ * HW_;          // 16 floats
  float2* partials = (float2*)(stats + 16);            // 36864 float2

  const int nblocks = (N_ * CHW_) / 256;               // 36864

  k_dwconv<<<nblocks, 256, 0, stream>>>(x, dw_w, dw_b, x1, partials);
  k_stats<<<N_, 256, 0, stream>>>(partials, stats);
  k_transpose<<<dim3(HW_ / 32, C_ / 32, N_), dim3(32, 8), 0, stream>>>(x, xv);
  k_norm_gelu<<<(N_ * CHW_) / 256, 256, 0, stream>>>(x1, stats, gn_w, gn_b);
  k_gemm<<<dim3(HW_ / 128, OM_ / 54, N_), 256, 0, stream>>>(x1, om_w, om_b, om);
  k_sample<<<2304, 256, 0, stream>>>(xv, om, out);
}

// Round 3
// 350.898 us; speedup vs baseline: 4.0042x; 1.4096x over previous
//
#include <hip/hip_runtime.h>

#define N_   8
#define C_   128
#define H_   96
#define W_   96
#define G_   8
#define GC_  16
#define HW_  (H_ * W_)       // 9216
#define CHW_ (C_ * HW_)      // 1179648
#define OM_  216
#define EPS_ 1e-5f
#define BLKS_PER_N_ (CHW_ / 256)   // 4608

// ---------------------------------------------------------------------------
// K1: depthwise 3x3 conv + bias (NCHW -> NCHW) + per-BLOCK sum/sumsq partials
// ---------------------------------------------------------------------------
__global__ __launch_bounds__(256) void k_dwconv(const float* __restrict__ x,
                                                const float* __restrict__ dw_w,
                                                const float* __restrict__ dw_b,
                                                float* __restrict__ x1,
                                                float2* __restrict__ partials) {
  int tid = threadIdx.x;
  int idx = blockIdx.x * 256 + tid;
  int n = idx / CHW_;
  int r = idx - n * CHW_;
  int c = r / HW_;
  int p = r - c * HW_;
  int h = p / W_;
  int w = p - h * W_;

  const float* wp = dw_w + c * 9;
  const float* xp = x + (n * C_ + c) * HW_;
  float acc = dw_b[c];
#pragma unroll
  for (int dy = 0; dy < 3; ++dy) {
#pragma unroll
    for (int dx = 0; dx < 3; ++dx) {
      int yy = h + dy - 1;
      int xx = w + dx - 1;
      bool v = (yy >= 0) & (yy < H_) & (xx >= 0) & (xx < W_);
      float xin = v ? xp[yy * W_ + xx] : 0.0f;
      acc = fmaf(xin, wp[dy * 3 + dx], acc);
    }
  }
  x1[idx] = acc;

  float s = acc;
  float q = acc * acc;
#pragma unroll
  for (int o = 32; o > 0; o >>= 1) {
    s += __shfl_down(s, o);
    q += __shfl_down(q, o);
  }
  __shared__ float ls[4], lq[4];
  int lane = tid & 63;
  int wv = tid >> 6;
  if (lane == 0) { ls[wv] = s; lq[wv] = q; }
  __syncthreads();
  if (tid == 0) {
    float ts = ls[0] + ls[1] + ls[2] + ls[3];
    float tq = lq[0] + lq[1] + lq[2] + lq[3];
    partials[blockIdx.x] = make_float2(ts, tq);
  }
}

// ---------------------------------------------------------------------------
// K1b: reduce 4608 per-block partials per sample -> stats[n] = (sum, sumsq)
// ---------------------------------------------------------------------------
__global__ __launch_bounds__(256) void k_stats(const float2* __restrict__ partials,
                                               float* __restrict__ stats) {
  int n = blockIdx.x;
  int tid = threadIdx.x;
  const float2* p = partials + n * BLKS_PER_N_;
  float s = 0.0f, q = 0.0f;
  for (int i = tid; i < BLKS_PER_N_; i += 256) {
    float2 v = p[i];
    s += v.x;
    q += v.y;
  }
#pragma unroll
  for (int o = 32; o > 0; o >>= 1) {
    s += __shfl_down(s, o);
    q += __shfl_down(q, o);
  }
  __shared__ float ls[4], lq[4];
  int lane = tid & 63;
  int wv = tid >> 6;
  if (lane == 0) { ls[wv] = s; lq[wv] = q; }
  __syncthreads();
  if (tid == 0) {
    stats[n * 2 + 0] = ls[0] + ls[1] + ls[2] + ls[3];
    stats[n * 2 + 1] = lq[0] + lq[1] + lq[2] + lq[3];
  }
}

// ---------------------------------------------------------------------------
// K2: transpose x NCHW -> group-planar xg[n][g][hw][16].
// Each (n,g) plane is contiguous (2.36 MB); pixel rows are 64 B.
// Grid: (HW/32=288, C/32=4, N=8), block (32,8)
// ---------------------------------------------------------------------------
__global__ __launch_bounds__(256) void k_transpose(const float* __restrict__ x,
                                                   float* __restrict__ xg) {
  __shared__ float tile[32][33];
  int tx = threadIdx.x;
  int ty = threadIdx.y;
  int p0 = blockIdx.x * 32;
  int c0 = blockIdx.y * 32;
  int n = blockIdx.z;
#pragma unroll
  for (int i = 0; i < 4; ++i) {
    int c = c0 + ty + i * 8;
    tile[ty + i * 8][tx] = x[(n * C_ + c) * HW_ + p0 + tx];
  }
  __syncthreads();
  int c = c0 + tx;
  int g = c >> 4;        // group of this channel
  int cc = c & 15;       // channel within group
#pragma unroll
  for (int i = 0; i < 4; ++i) {
    int p = p0 + ty + i * 8;
    xg[(((size_t)(n * G_ + g) * HW_) + p) * GC_ + cc] = tile[tx][ty + i * 8];
  }
}

// ---------------------------------------------------------------------------
// K3: per-sample layernorm + affine + exact GELU, in-place on x1
// ---------------------------------------------------------------------------
__global__ __launch_bounds__(256) void k_norm_gelu(float* __restrict__ x1,
                                                   const float* __restrict__ stats,
                                                   const float* __restrict__ gn_w,
                                                   const float* __restrict__ gn_b) {
  int idx = blockIdx.x * 256 + threadIdx.x;
  int n = idx / CHW_;
  int c = (idx - n * CHW_) / HW_;
  float s = stats[n * 2 + 0];
  float q = stats[n * 2 + 1];
  const float inv = 1.0f / (float)CHW_;
  float mean = s * inv;
  float var = q * inv - mean * mean;
  float rstd = rsqrtf(var + EPS_);
  float v = (x1[idx] - mean) * rstd * gn_w[c] + gn_b[c];
  float g = 0.5f * v * (1.0f + erff(v * 0.70710678118654752f));
  x1[idx] = g;
}

// ---------------------------------------------------------------------------
// K4: om[n,o,p] = sum_c om_w[o,c] * x1n[n,c,p] + om_b[o]
// ---------------------------------------------------------------------------
__global__ __launch_bounds__(256) void k_gemm(const float* __restrict__ B,
                                              const float* __restrict__ Aw,
                                              const float* __restrict__ bias,
                                              float* __restrict__ Cm) {
  __shared__ float As[54 * 128];
  int tid = threadIdx.x;
  int ct = blockIdx.x;
  int rt = blockIdx.y;
  int n = blockIdx.z;
  int r0 = rt * 54;

  for (int i = tid; i < 54 * 128; i += 256) As[i] = Aw[r0 * 128 + i];
  __syncthreads();

  int half = tid >> 7;                  // wave-uniform
  int col = (tid & 127) + ct * 128;
  int rbase = half * 27;

  const float* Bp = B + n * CHW_ + col;
  float acc[27];
#pragma unroll
  for (int r = 0; r < 27; ++r) acc[r] = bias[r0 + rbase + r];

  for (int c = 0; c < 128; c += 4) {
    float b0 = Bp[(c + 0) * HW_];
    float b1 = Bp[(c + 1) * HW_];
    float b2 = Bp[(c + 2) * HW_];
    float b3 = Bp[(c + 3) * HW_];
#pragma unroll
    for (int r = 0; r < 27; ++r) {
      const float4 a = *(const float4*)&As[(rbase + r) * 128 + c];
      acc[r] = fmaf(a.x, b0, acc[r]);
      acc[r] = fmaf(a.y, b1, acc[r]);
      acc[r] = fmaf(a.z, b2, acc[r]);
      acc[r] = fmaf(a.w, b3, acc[r]);
    }
  }

  float* Cp = Cm + (n * OM_ + r0 + rbase) * HW_ + col;
#pragma unroll
  for (int r = 0; r < 27; ++r) Cp[r * HW_] = acc[r];
}

// ---------------------------------------------------------------------------
// K5: deformable bilinear sampling from group-planar xg.
// Block swizzle: n = blockIdx%8 (pins a sample to one XCD under round-robin
// dispatch), g next-fastest, p-block slowest -> co-resident per-XCD working
// set ~1.2 MB (fits 4 MB L2).
// Grid: 2304 blocks of 256 = 8n x 8g x 36 p-blocks.
// ---------------------------------------------------------------------------
__global__ __launch_bounds__(256) void k_sample(const float* __restrict__ xg,
                                                const float* __restrict__ om,
                                                float* __restrict__ out) {
  int tid = threadIdx.x;
  int ord = blockIdx.x;
  int n = ord & 7;
  int t2 = ord >> 3;
  int g = t2 & 7;
  int pb = t2 >> 3;
  int p = pb * 256 + tid;
  int h = p / W_;
  int w = p - h * W_;

  const float* omp = om + (n * OM_ + g * 27) * HW_ + p;
  float v[27];
#pragma unroll
  for (int j = 0; j < 27; ++j) v[j] = omp[j * HW_];

  float4 a0 = {0, 0, 0, 0}, a1 = {0, 0, 0, 0}, a2 = {0, 0, 0, 0}, a3 = {0, 0, 0, 0};
  const float* xb = xg + ((size_t)(n * G_ + g) * HW_) * GC_;

#pragma unroll
  for (int k = 0; k < 9; ++k) {
    float offx = v[2 * k + 0];
    float offy = v[2 * k + 1];
    float m = v[18 + k];
    float locy = (float)(h + k / 3 - 1) + offy;
    float locx = (float)(w + k % 3 - 1) + offx;
    float y0f = floorf(locy);
    float x0f = floorf(locx);
    float ly = locy - y0f;
    float lx = locx - x0f;
    int y0 = (int)y0f;
    int x0 = (int)x0f;
    float wts[4] = {(1.0f - ly) * (1.0f - lx) * m, (1.0f - ly) * lx * m,
                    ly * (1.0f - lx) * m, ly * lx * m};
#pragma unroll
    for (int cor = 0; cor < 4; ++cor) {
      int yy = y0 + (cor >> 1);
      int xx = x0 + (cor & 1);
      bool valid = (yy >= 0) & (yy < H_) & (xx >= 0) & (xx < W_);
      float wt = valid ? wts[cor] : 0.0f;
      int yc = min(max(yy, 0), H_ - 1);
      int xc = min(max(xx, 0), W_ - 1);
      const float4* src = (const float4*)(xb + (yc * W_ + xc) * GC_);
      float4 s0 = src[0], s1 = src[1], s2 = src[2], s3 = src[3];
      a0.x = fmaf(wt, s0.x, a0.x); a0.y = fmaf(wt, s0.y, a0.y);
      a0.z = fmaf(wt, s0.z, a0.z); a0.w = fmaf(wt, s0.w, a0.w);
      a1.x = fmaf(wt, s1.x, a1.x); a1.y = fmaf(wt, s1.y, a1.y);
      a1.z = fmaf(wt, s1.z, a1.z); a1.w = fmaf(wt, s1.w, a1.w);
      a2.x = fmaf(wt, s2.x, a2.x); a2.y = fmaf(wt, s2.y, a2.y);
      a2.z = fmaf(wt, s2.z, a2.z); a2.w = fmaf(wt, s2.w, a2.w);
      a3.x = fmaf(wt, s3.x, a3.x); a3.y = fmaf(wt, s3.y, a3.y);
      a3.z = fmaf(wt, s3.z, a3.z); a3.w = fmaf(wt, s3.w, a3.w);
    }
  }

  float* op = out + (n * C_ + g * GC_) * HW_ + p;
  op[0 * HW_]  = a0.x; op[1 * HW_]  = a0.y; op[2 * HW_]  = a0.z; op[3 * HW_]  = a0.w;
  op[4 * HW_]  = a1.x; op[5 * HW_]  = a1.y; op[6 * HW_]  = a1.z; op[7 * HW_]  = a1.w;
  op[8 * HW_]  = a2.x; op[9 * HW_]  = a2.y; op[10 * HW_] = a2.z; op[11 * HW_] = a2.w;
  op[12 * HW_] = a3.x; op[13 * HW_] = a3.y; op[14 * HW_] = a3.z; op[15 * HW_] = a3.w;
}

// ---------------------------------------------------------------------------
extern "C" void kernel_launch(void* const* d_in, const int* in_sizes, int n_in,
                              void* d_out, int out_size, void* d_ws, size_t ws_size,
                              hipStream_t stream) {
  const float* x    = (const float*)d_in[0];
  const float* dw_w = (const float*)d_in[1];
  const float* dw_b = (const float*)d_in[2];
  const float* gn_w = (const float*)d_in[3];
  const float* gn_b = (const float*)d_in[4];
  const float* om_w = (const float*)d_in[5];
  const float* om_b = (const float*)d_in[6];
  float* out = (float*)d_out;

  float* ws = (float*)d_ws;
  float* x1 = ws;                        // N*C*H*W      = 9437184 floats
  float* xg = x1 + (size_t)N_ * CHW_;    // N*G*HW*16    = 9437184 floats
  float* om = xg + (size_t)N_ * CHW_;    // N*216*HW     = 15925248 floats
  float* stats = om + (size_t)N_ * OM_ * HW_;          // 16 floats
  float2* partials = (float2*)(stats + 16);            // 36864 float2

  const int nblocks = (N_ * CHW_) / 256;               // 36864

  k_dwconv<<<nblocks, 256, 0, stream>>>(x, dw_w, dw_b, x1, partials);
  k_stats<<<N_, 256, 0, stream>>>(partials, stats);
  k_transpose<<<dim3(HW_ / 32, C_ / 32, N_), dim3(32, 8), 0, stream>>>(x, xg);
  k_norm_gelu<<<(N_ * CHW_) / 256, 256, 0, stream>>>(x1, stats, gn_w, gn_b);
  k_gemm<<<dim3(HW_ / 128, OM_ / 54, N_), 256, 0, stream>>>(x1, om_w, om_b, om);
  k_sample<<<2304, 256, 0, stream>>>(xg, om, out);
}

// Round 4
// 285.279 us; speedup vs baseline: 4.9252x; 1.2300x over previous
//
#include <hip/hip_runtime.h>

#define N_   8
#define C_   128
#define H_   96
#define W_   96
#define G_   8
#define GC_  16
#define HW_  (H_ * W_)       // 9216
#define CHW_ (C_ * HW_)      // 1179648
#define OM_  216
#define EPS_ 1e-5f
#define BLKS_PER_N_ (CHW_ / 256)   // 4608

// ---------------------------------------------------------------------------
// K1: depthwise 3x3 conv + bias (NCHW -> NCHW) + per-BLOCK sum/sumsq partials
// ---------------------------------------------------------------------------
__global__ __launch_bounds__(256) void k_dwconv(const float* __restrict__ x,
                                                const float* __restrict__ dw_w,
                                                const float* __restrict__ dw_b,
                                                float* __restrict__ x1,
                                                float2* __restrict__ partials) {
  int tid = threadIdx.x;
  int idx = blockIdx.x * 256 + tid;
  int n = idx / CHW_;
  int r = idx - n * CHW_;
  int c = r / HW_;
  int p = r - c * HW_;
  int h = p / W_;
  int w = p - h * W_;

  const float* wp = dw_w + c * 9;
  const float* xp = x + (n * C_ + c) * HW_;
  float acc = dw_b[c];
#pragma unroll
  for (int dy = 0; dy < 3; ++dy) {
#pragma unroll
    for (int dx = 0; dx < 3; ++dx) {
      int yy = h + dy - 1;
      int xx = w + dx - 1;
      bool v = (yy >= 0) & (yy < H_) & (xx >= 0) & (xx < W_);
      float xin = v ? xp[yy * W_ + xx] : 0.0f;
      acc = fmaf(xin, wp[dy * 3 + dx], acc);
    }
  }
  x1[idx] = acc;

  float s = acc;
  float q = acc * acc;
#pragma unroll
  for (int o = 32; o > 0; o >>= 1) {
    s += __shfl_down(s, o);
    q += __shfl_down(q, o);
  }
  __shared__ float ls[4], lq[4];
  int lane = tid & 63;
  int wv = tid >> 6;
  if (lane == 0) { ls[wv] = s; lq[wv] = q; }
  __syncthreads();
  if (tid == 0) {
    float ts = ls[0] + ls[1] + ls[2] + ls[3];
    float tq = lq[0] + lq[1] + lq[2] + lq[3];
    partials[blockIdx.x] = make_float2(ts, tq);
  }
}

// ---------------------------------------------------------------------------
// K1b: reduce 4608 per-block partials per sample -> stats[n] = (sum, sumsq)
// ---------------------------------------------------------------------------
__global__ __launch_bounds__(256) void k_stats(const float2* __restrict__ partials,
                                               float* __restrict__ stats) {
  int n = blockIdx.x;
  int tid = threadIdx.x;
  const float2* p = partials + n * BLKS_PER_N_;
  float s = 0.0f, q = 0.0f;
  for (int i = tid; i < BLKS_PER_N_; i += 256) {
    float2 v = p[i];
    s += v.x;
    q += v.y;
  }
#pragma unroll
  for (int o = 32; o > 0; o >>= 1) {
    s += __shfl_down(s, o);
    q += __shfl_down(q, o);
  }
  __shared__ float ls[4], lq[4];
  int lane = tid & 63;
  int wv = tid >> 6;
  if (lane == 0) { ls[wv] = s; lq[wv] = q; }
  __syncthreads();
  if (tid == 0) {
    stats[n * 2 + 0] = ls[0] + ls[1] + ls[2] + ls[3];
    stats[n * 2 + 1] = lq[0] + lq[1] + lq[2] + lq[3];
  }
}

// ---------------------------------------------------------------------------
// K2: transpose x NCHW -> group-planar xg[n][g][hw][16]
// ---------------------------------------------------------------------------
__global__ __launch_bounds__(256) void k_transpose(const float* __restrict__ x,
                                                   float* __restrict__ xg) {
  __shared__ float tile[32][33];
  int tx = threadIdx.x;
  int ty = threadIdx.y;
  int p0 = blockIdx.x * 32;
  int c0 = blockIdx.y * 32;
  int n = blockIdx.z;
#pragma unroll
  for (int i = 0; i < 4; ++i) {
    int c = c0 + ty + i * 8;
    tile[ty + i * 8][tx] = x[(n * C_ + c) * HW_ + p0 + tx];
  }
  __syncthreads();
  int c = c0 + tx;
  int g = c >> 4;
  int cc = c & 15;
#pragma unroll
  for (int i = 0; i < 4; ++i) {
    int p = p0 + ty + i * 8;
    xg[(((size_t)(n * G_ + g) * HW_) + p) * GC_ + cc] = tile[tx][ty + i * 8];
  }
}

// ---------------------------------------------------------------------------
// K3: per-sample layernorm + affine + exact GELU, in-place on x1
// ---------------------------------------------------------------------------
__global__ __launch_bounds__(256) void k_norm_gelu(float* __restrict__ x1,
                                                   const float* __restrict__ stats,
                                                   const float* __restrict__ gn_w,
                                                   const float* __restrict__ gn_b) {
  int idx = blockIdx.x * 256 + threadIdx.x;
  int n = idx / CHW_;
  int c = (idx - n * CHW_) / HW_;
  float s = stats[n * 2 + 0];
  float q = stats[n * 2 + 1];
  const float inv = 1.0f / (float)CHW_;
  float mean = s * inv;
  float var = q * inv - mean * mean;
  float rstd = rsqrtf(var + EPS_);
  float v = (x1[idx] - mean) * rstd * gn_w[c] + gn_b[c];
  float g = 0.5f * v * (1.0f + erff(v * 0.70710678118654752f));
  x1[idx] = g;
}

// ---------------------------------------------------------------------------
// K4: om[n,o,p] = sum_c om_w[o,c] * x1n[n,c,p] + om_b[o]
// ---------------------------------------------------------------------------
__global__ __launch_bounds__(256) void k_gemm(const float* __restrict__ B,
                                              const float* __restrict__ Aw,
                                              const float* __restrict__ bias,
                                              float* __restrict__ Cm) {
  __shared__ float As[54 * 128];
  int tid = threadIdx.x;
  int ct = blockIdx.x;
  int rt = blockIdx.y;
  int n = blockIdx.z;
  int r0 = rt * 54;

  for (int i = tid; i < 54 * 128; i += 256) As[i] = Aw[r0 * 128 + i];
  __syncthreads();

  int half = tid >> 7;
  int col = (tid & 127) + ct * 128;
  int rbase = half * 27;

  const float* Bp = B + n * CHW_ + col;
  float acc[27];
#pragma unroll
  for (int r = 0; r < 27; ++r) acc[r] = bias[r0 + rbase + r];

  for (int c = 0; c < 128; c += 4) {
    float b0 = Bp[(c + 0) * HW_];
    float b1 = Bp[(c + 1) * HW_];
    float b2 = Bp[(c + 2) * HW_];
    float b3 = Bp[(c + 3) * HW_];
#pragma unroll
    for (int r = 0; r < 27; ++r) {
      const float4 a = *(const float4*)&As[(rbase + r) * 128 + c];
      acc[r] = fmaf(a.x, b0, acc[r]);
      acc[r] = fmaf(a.y, b1, acc[r]);
      acc[r] = fmaf(a.z, b2, acc[r]);
      acc[r] = fmaf(a.w, b3, acc[r]);
    }
  }

  float* Cp = Cm + (n * OM_ + r0 + rbase) * HW_ + col;
#pragma unroll
  for (int r = 0; r < 27; ++r) Cp[r * HW_] = acc[r];
}

// ---------------------------------------------------------------------------
// K5: deformable bilinear sampling, two-phase.
// Block = 64 pixels. Phase 1: 576 (pixel,point) jobs compute 4 weights +
// 4 clamped element-offsets once, into LDS. Phase 2: wave = 16 pixels x
// 4 chunk-lanes; each corner gather is ONE dwordx4 per lane with 4
// consecutive lanes covering one pixel's full 64 B line (4x fewer L1
// transactions than thread-per-pixel).
// Grid: 9216 blocks = 8n (fastest, XCD-pinning) x 8g x 144 p-blocks.
// ---------------------------------------------------------------------------
__global__ __launch_bounds__(256) void k_sample(const float* __restrict__ xg,
                                                const float* __restrict__ om,
                                                float* __restrict__ out) {
  __shared__ float4 s_w[9 * 64];   // weights (w00,w01,w10,w11) per (pt,px)
  __shared__ int4   s_a[9 * 64];   // float-element offsets per corner

  int tid = threadIdx.x;
  int ord = blockIdx.x;
  int n = ord & 7;
  int t2 = ord >> 3;
  int g = t2 & 7;
  int pb = t2 >> 3;                // 0..143, 64 pixels each
  int p0 = pb * 64;

  // ---- Phase 1: 576 jobs (pt = j>>6, px = j&63) ----
  const float* omb = om + (n * OM_ + g * 27) * HW_ + p0;
  for (int j = tid; j < 576; j += 256) {
    int pt = j >> 6;
    int px = j & 63;
    int p = p0 + px;
    int h = p / W_;
    int w = p - h * W_;
    float offx = omb[(2 * pt) * HW_ + px];
    float offy = omb[(2 * pt + 1) * HW_ + px];
    float m    = omb[(18 + pt) * HW_ + px];
    float locy = (float)(h + pt / 3 - 1) + offy;
    float locx = (float)(w + pt % 3 - 1) + offx;
    float y0f = floorf(locy);
    float x0f = floorf(locx);
    float ly = locy - y0f;
    float lx = locx - x0f;
    int y0 = (int)y0f;
    int x0 = (int)x0f;
    int y1 = y0 + 1;
    int x1 = x0 + 1;
    bool vy0 = (y0 >= 0) & (y0 < H_);
    bool vy1 = (y1 >= 0) & (y1 < H_);
    bool vx0 = (x0 >= 0) & (x0 < W_);
    bool vx1 = (x1 >= 0) & (x1 < W_);
    int yc0 = min(max(y0, 0), H_ - 1);
    int yc1 = min(max(y1, 0), H_ - 1);
    int xc0 = min(max(x0, 0), W_ - 1);
    int xc1 = min(max(x1, 0), W_ - 1);
    float t0 = (1.0f - ly) * m;
    float t1 = ly * m;
    float u0 = 1.0f - lx;
    float4 wv;
    wv.x = (vy0 & vx0) ? t0 * u0 : 0.0f;
    wv.y = (vy0 & vx1) ? t0 * lx : 0.0f;
    wv.z = (vy1 & vx0) ? t1 * u0 : 0.0f;
    wv.w = (vy1 & vx1) ? t1 * lx : 0.0f;
    int4 av;
    av.x = (yc0 * W_ + xc0) * GC_;
    av.y = (yc0 * W_ + xc1) * GC_;
    av.z = (yc1 * W_ + xc0) * GC_;
    av.w = (yc1 * W_ + xc1) * GC_;
    s_w[j] = wv;
    s_a[j] = av;
  }
  __syncthreads();

  // ---- Phase 2: wave = 16 pixels x 4 chunk-lanes ----
  int px_l = tid >> 2;             // 0..63
  int ch = tid & 3;                // chunk: channels ch*4 .. ch*4+3
  int p = p0 + px_l;
  const float* xb = xg + ((size_t)(n * G_ + g) * HW_) * GC_ + ch * 4;

  float4 acc = {0.0f, 0.0f, 0.0f, 0.0f};
#pragma unroll
  for (int pt = 0; pt < 9; ++pt) {
    float4 wv = s_w[pt * 64 + px_l];
    int4 av = s_a[pt * 64 + px_l];
    float4 s00 = *(const float4*)(xb + av.x);
    float4 s01 = *(const float4*)(xb + av.y);
    float4 s10 = *(const float4*)(xb + av.z);
    float4 s11 = *(const float4*)(xb + av.w);
    acc.x = fmaf(wv.x, s00.x, acc.x); acc.y = fmaf(wv.x, s00.y, acc.y);
    acc.z = fmaf(wv.x, s00.z, acc.z); acc.w = fmaf(wv.x, s00.w, acc.w);
    acc.x = fmaf(wv.y, s01.x, acc.x); acc.y = fmaf(wv.y, s01.y, acc.y);
    acc.z = fmaf(wv.y, s01.z, acc.z); acc.w = fmaf(wv.y, s01.w, acc.w);
    acc.x = fmaf(wv.z, s10.x, acc.x); acc.y = fmaf(wv.z, s10.y, acc.y);
    acc.z = fmaf(wv.z, s10.z, acc.z); acc.w = fmaf(wv.z, s10.w, acc.w);
    acc.x = fmaf(wv.w, s11.x, acc.x); acc.y = fmaf(wv.w, s11.y, acc.y);
    acc.z = fmaf(wv.w, s11.z, acc.z); acc.w = fmaf(wv.w, s11.w, acc.w);
  }

  float* op = out + ((size_t)(n * C_ + g * GC_ + ch * 4)) * HW_ + p;
  op[0 * HW_] = acc.x;
  op[1 * HW_] = acc.y;
  op[2 * HW_] = acc.z;
  op[3 * HW_] = acc.w;
}

// ---------------------------------------------------------------------------
extern "C" void kernel_launch(void* const* d_in, const int* in_sizes, int n_in,
                              void* d_out, int out_size, void* d_ws, size_t ws_size,
                              hipStream_t stream) {
  const float* x    = (const float*)d_in[0];
  const float* dw_w = (const float*)d_in[1];
  const float* dw_b = (const float*)d_in[2];
  const float* gn_w = (const float*)d_in[3];
  const float* gn_b = (const float*)d_in[4];
  const float* om_w = (const float*)d_in[5];
  const float* om_b = (const float*)d_in[6];
  float* out = (float*)d_out;

  float* ws = (float*)d_ws;
  float* x1 = ws;                        // N*C*H*W      = 9437184 floats
  float* xg = x1 + (size_t)N_ * CHW_;    // N*G*HW*16    = 9437184 floats
  float* om = xg + (size_t)N_ * CHW_;    // N*216*HW     = 15925248 floats
  float* stats = om + (size_t)N_ * OM_ * HW_;          // 16 floats
  float2* partials = (float2*)(stats + 16);            // 36864 float2

  const int nblocks = (N_ * CHW_) / 256;               // 36864

  k_dwconv<<<nblocks, 256, 0, stream>>>(x, dw_w, dw_b, x1, partials);
  k_stats<<<N_, 256, 0, stream>>>(partials, stats);
  k_transpose<<<dim3(HW_ / 32, C_ / 32, N_), dim3(32, 8), 0, stream>>>(x, xg);
  k_norm_gelu<<<(N_ * CHW_) / 256, 256, 0, stream>>>(x1, stats, gn_w, gn_b);
  k_gemm<<<dim3(HW_ / 128, OM_ / 54, N_), 256, 0, stream>>>(x1, om_w, om_b, om);
  k_sample<<<9216, 256, 0, stream>>>(xg, om, out);
}

// Round 5
// 255.639 us; speedup vs baseline: 5.4963x; 1.1159x over previous
//
#include <hip/hip_runtime.h>

#define N_   8
#define C_   128
#define H_   96
#define W_   96
#define G_   8
#define GC_  16
#define HW_  (H_ * W_)       // 9216
#define CHW_ (C_ * HW_)      // 1179648
#define OM_  216
#define OMP_ 224             // padded o-rows for 16-row MFMA tiles
#define EPS_ 1e-5f
#define BLKS_PER_N_ (CHW_ / 256)   // 4608

typedef short bf16x8 __attribute__((ext_vector_type(8)));
typedef float f32x4 __attribute__((ext_vector_type(4)));

static __device__ __forceinline__ unsigned short f2bf(float f) {
  unsigned int u = __float_as_uint(f);
  unsigned int r = (u + 0x7fffu + ((u >> 16) & 1u)) >> 16;
  return (unsigned short)r;
}

// ---------------------------------------------------------------------------
// K1: depthwise 3x3 conv + bias, STATS ONLY (no x1 write).
// Per-block (one (n,c) slice) sum/sumsq partials.
// ---------------------------------------------------------------------------
__global__ __launch_bounds__(256) void k_stats_conv(const float* __restrict__ x,
                                                    const float* __restrict__ dw_w,
                                                    const float* __restrict__ dw_b,
                                                    float2* __restrict__ partials) {
  int tid = threadIdx.x;
  int idx = blockIdx.x * 256 + tid;
  int n = idx / CHW_;
  int r = idx - n * CHW_;
  int c = r / HW_;
  int p = r - c * HW_;
  int h = p / W_;
  int w = p - h * W_;

  const float* wp = dw_w + c * 9;
  const float* xp = x + (n * C_ + c) * HW_;
  float acc = dw_b[c];
#pragma unroll
  for (int dy = 0; dy < 3; ++dy) {
#pragma unroll
    for (int dx = 0; dx < 3; ++dx) {
      int yy = h + dy - 1;
      int xx = w + dx - 1;
      bool v = (yy >= 0) & (yy < H_) & (xx >= 0) & (xx < W_);
      float xin = v ? xp[yy * W_ + xx] : 0.0f;
      acc = fmaf(xin, wp[dy * 3 + dx], acc);
    }
  }

  float s = acc;
  float q = acc * acc;
#pragma unroll
  for (int o = 32; o > 0; o >>= 1) {
    s += __shfl_down(s, o);
    q += __shfl_down(q, o);
  }
  __shared__ float ls[4], lq[4];
  int lane = tid & 63;
  int wv = tid >> 6;
  if (lane == 0) { ls[wv] = s; lq[wv] = q; }
  __syncthreads();
  if (tid == 0) {
    partials[blockIdx.x] = make_float2(ls[0] + ls[1] + ls[2] + ls[3],
                                       lq[0] + lq[1] + lq[2] + lq[3]);
  }
}

// ---------------------------------------------------------------------------
// K1b: reduce 4608 per-block partials per sample -> stats[n] = (sum, sumsq)
// ---------------------------------------------------------------------------
__global__ __launch_bounds__(256) void k_stats(const float2* __restrict__ partials,
                                               float* __restrict__ stats) {
  int n = blockIdx.x;
  int tid = threadIdx.x;
  const float2* p = partials + n * BLKS_PER_N_;
  float s = 0.0f, q = 0.0f;
  for (int i = tid; i < BLKS_PER_N_; i += 256) {
    float2 v = p[i];
    s += v.x;
    q += v.y;
  }
#pragma unroll
  for (int o = 32; o > 0; o >>= 1) {
    s += __shfl_down(s, o);
    q += __shfl_down(q, o);
  }
  __shared__ float ls[4], lq[4];
  int lane = tid & 63;
  int wv = tid >> 6;
  if (lane == 0) { ls[wv] = s; lq[wv] = q; }
  __syncthreads();
  if (tid == 0) {
    stats[n * 2 + 0] = ls[0] + ls[1] + ls[2] + ls[3];
    stats[n * 2 + 1] = lq[0] + lq[1] + lq[2] + lq[3];
  }
}

// ---------------------------------------------------------------------------
// K1c: om_w (216x128 f32) -> A bf16 padded to 224x128 (pad rows zero).
// ---------------------------------------------------------------------------
__global__ __launch_bounds__(256) void k_prep(const float* __restrict__ om_w,
                                              unsigned short* __restrict__ A) {
  int idx = blockIdx.x * 256 + threadIdx.x;   // 0 .. 224*128-1
  int o = idx >> 7;
  float v = (o < OM_) ? om_w[idx] : 0.0f;
  A[idx] = f2bf(v);
}

// ---------------------------------------------------------------------------
// K2: transpose x NCHW -> group-planar xg[n][g][hw][16] (f32, for sampler)
// ---------------------------------------------------------------------------
__global__ __launch_bounds__(256) void k_transpose(const float* __restrict__ x,
                                                   float* __restrict__ xg) {
  __shared__ float tile[32][33];
  int tx = threadIdx.x;
  int ty = threadIdx.y;
  int p0 = blockIdx.x * 32;
  int c0 = blockIdx.y * 32;
  int n = blockIdx.z;
#pragma unroll
  for (int i = 0; i < 4; ++i) {
    int c = c0 + ty + i * 8;
    tile[ty + i * 8][tx] = x[(n * C_ + c) * HW_ + p0 + tx];
  }
  __syncthreads();
  int c = c0 + tx;
  int g = c >> 4;
  int cc = c & 15;
#pragma unroll
  for (int i = 0; i < 4; ++i) {
    int p = p0 + ty + i * 8;
    xg[(((size_t)(n * G_ + g) * HW_) + p) * GC_ + cc] = tile[tx][ty + i * 8];
  }
}

// ---------------------------------------------------------------------------
// K3: recompute conv (bitwise-same FMA order as k_stats_conv) + layernorm +
// GELU + bf16 cast + transpose -> x1b NHWC bf16 [n][p][c].
// Grid: (288, 4, 8), block (32,8). Tile 32c x 32p via LDS.
// ---------------------------------------------------------------------------
__global__ __launch_bounds__(256) void k_norm_gelu_t(const float* __restrict__ x,
                                                     const float* __restrict__ dw_w,
                                                     const float* __restrict__ dw_b,
                                                     const float* __restrict__ stats,
                                                     const float* __restrict__ gn_w,
                                                     const float* __restrict__ gn_b,
                                                     unsigned short* __restrict__ x1b) {
  __shared__ float tile[32][33];
  int tx = threadIdx.x;
  int ty = threadIdx.y;
  int p0 = blockIdx.x * 32;
  int c0 = blockIdx.y * 32;
  int n = blockIdx.z;

  float s = stats[n * 2 + 0];
  float q = stats[n * 2 + 1];
  const float inv = 1.0f / (float)CHW_;
  float mean = s * inv;
  float var = q * inv - mean * mean;
  float rstd = rsqrtf(var + EPS_);

  int p = p0 + tx;
  int h = p / W_;
  int w = p - h * W_;

#pragma unroll
  for (int i = 0; i < 4; ++i) {
    int c = c0 + ty + i * 8;
    const float* wp = dw_w + c * 9;
    const float* xp = x + (n * C_ + c) * HW_;
    float acc = dw_b[c];
#pragma unroll
    for (int dy = 0; dy < 3; ++dy) {
#pragma unroll
      for (int dx = 0; dx < 3; ++dx) {
        int yy = h + dy - 1;
        int xx = w + dx - 1;
        bool vok = (yy >= 0) & (yy < H_) & (xx >= 0) & (xx < W_);
        float xin = vok ? xp[yy * W_ + xx] : 0.0f;
        acc = fmaf(xin, wp[dy * 3 + dx], acc);
      }
    }
    float v = (acc - mean) * rstd * gn_w[c] + gn_b[c];
    float g = 0.5f * v * (1.0f + erff(v * 0.70710678118654752f));
    tile[ty + i * 8][tx] = g;
  }
  __syncthreads();
#pragma unroll
  for (int i = 0; i < 4; ++i) {
    int pp = p0 + ty + i * 8;
    x1b[((size_t)(n * HW_) + pp) * C_ + c0 + tx] = f2bf(tile[tx][ty + i * 8]);
  }
}

// ---------------------------------------------------------------------------
// K4: MFMA GEMM. om[n,o,p] = sum_c om_w[o,c]*x1[n,c,p] + om_b[o], bf16 inputs,
// f32 accumulate. Block = 128-pixel slab x all 224 o (stores guarded <216).
// B slab (128p x 128c bf16 = 32KB) staged in LDS; each wave holds its 8
// B-frags in regs; per o-tile: 4 A-frag loads (L2-hot) + 8 MFMA.
// Grid: (72, 8), 256 threads.
// ---------------------------------------------------------------------------
__global__ __launch_bounds__(256) void k_gemm_mfma(const unsigned short* __restrict__ Bt,
                                                   const unsigned short* __restrict__ A,
                                                   const float* __restrict__ bias,
                                                   float* __restrict__ Cm) {
  __shared__ unsigned short Bl[128 * 136];   // row stride 272 B (16B-aligned, conflict-benign)
  int tid = threadIdx.x;
  int pb = blockIdx.x;
  int n = blockIdx.y;
  int p0 = pb * 128;

  // stage 32 KB contiguous slab -> LDS (row stride 136)
  const unsigned short* src = Bt + ((size_t)n * HW_ + p0) * C_;
#pragma unroll
  for (int i = 0; i < 8; ++i) {
    int idx = i * 256 + tid;          // 16B-chunk id
    int row = idx >> 4;
    int col = idx & 15;
    *(uint4*)(&Bl[row * 136 + col * 8]) = *(const uint4*)(src + row * C_ + col * 8);
  }
  __syncthreads();

  int wave = tid >> 6;
  int lane = tid & 63;
  int quad = lane >> 4;
  int l16 = lane & 15;
  int pw = wave * 32;

  // B-fragments: 2 p-subtiles x 4 k-steps, held in registers
  bf16x8 bfrag[2][4];
#pragma unroll
  for (int st = 0; st < 2; ++st) {
    int prow = pw + st * 16 + l16;
#pragma unroll
    for (int kk = 0; kk < 4; ++kk)
      bfrag[st][kk] = *(const bf16x8*)(&Bl[prow * 136 + kk * 32 + quad * 8]);
  }

  for (int ot = 0; ot < 14; ++ot) {
    const unsigned short* Ap = A + (ot * 16 + l16) * C_ + quad * 8;
    bf16x8 afrag[4];
#pragma unroll
    for (int kk = 0; kk < 4; ++kk)
      afrag[kk] = *(const bf16x8*)(Ap + kk * 32);

    f32x4 acc[2] = {{0.f, 0.f, 0.f, 0.f}, {0.f, 0.f, 0.f, 0.f}};
#pragma unroll
    for (int st = 0; st < 2; ++st)
#pragma unroll
      for (int kk = 0; kk < 4; ++kk)
        acc[st] = __builtin_amdgcn_mfma_f32_16x16x32_bf16(afrag[kk], bfrag[st][kk], acc[st], 0, 0, 0);

#pragma unroll
    for (int st = 0; st < 2; ++st) {
      int p = p0 + pw + st * 16 + l16;
#pragma unroll
      for (int r = 0; r < 4; ++r) {
        int o = ot * 16 + quad * 4 + r;
        if (o < OM_) Cm[((size_t)n * OM_ + o) * HW_ + p] = acc[st][r] + bias[o];
      }
    }
  }
}

// ---------------------------------------------------------------------------
// K5: deformable bilinear sampling, two-phase (unchanged from R4).
// ---------------------------------------------------------------------------
__global__ __launch_bounds__(256) void k_sample(const float* __restrict__ xg,
                                                const float* __restrict__ om,
                                                float* __restrict__ out) {
  __shared__ float4 s_w[9 * 64];
  __shared__ int4   s_a[9 * 64];

  int tid = threadIdx.x;
  int ord = blockIdx.x;
  int n = ord & 7;
  int t2 = ord >> 3;
  int g = t2 & 7;
  int pb = t2 >> 3;
  int p0 = pb * 64;

  const float* omb = om + (n * OM_ + g * 27) * HW_ + p0;
  for (int j = tid; j < 576; j += 256) {
    int pt = j >> 6;
    int px = j & 63;
    int p = p0 + px;
    int h = p / W_;
    int w = p - h * W_;
    float offx = omb[(2 * pt) * HW_ + px];
    float offy = omb[(2 * pt + 1) * HW_ + px];
    float m    = omb[(18 + pt) * HW_ + px];
    float locy = (float)(h + pt / 3 - 1) + offy;
    float locx = (float)(w + pt % 3 - 1) + offx;
    float y0f = floorf(locy);
    float x0f = floorf(locx);
    float ly = locy - y0f;
    float lx = locx - x0f;
    int y0 = (int)y0f;
    int x0 = (int)x0f;
    int y1 = y0 + 1;
    int x1 = x0 + 1;
    bool vy0 = (y0 >= 0) & (y0 < H_);
    bool vy1 = (y1 >= 0) & (y1 < H_);
    bool vx0 = (x0 >= 0) & (x0 < W_);
    bool vx1 = (x1 >= 0) & (x1 < W_);
    int yc0 = min(max(y0, 0), H_ - 1);
    int yc1 = min(max(y1, 0), H_ - 1);
    int xc0 = min(max(x0, 0), W_ - 1);
    int xc1 = min(max(x1, 0), W_ - 1);
    float t0 = (1.0f - ly) * m;
    float t1 = ly * m;
    float u0 = 1.0f - lx;
    float4 wv;
    wv.x = (vy0 & vx0) ? t0 * u0 : 0.0f;
    wv.y = (vy0 & vx1) ? t0 * lx : 0.0f;
    wv.z = (vy1 & vx0) ? t1 * u0 : 0.0f;
    wv.w = (vy1 & vx1) ? t1 * lx : 0.0f;
    int4 av;
    av.x = (yc0 * W_ + xc0) * GC_;
    av.y = (yc0 * W_ + xc1) * GC_;
    av.z = (yc1 * W_ + xc0) * GC_;
    av.w = (yc1 * W_ + xc1) * GC_;
    s_w[j] = wv;
    s_a[j] = av;
  }
  __syncthreads();

  int px_l = tid >> 2;
  int ch = tid & 3;
  int p = p0 + px_l;
  const float* xb = xg + ((size_t)(n * G_ + g) * HW_) * GC_ + ch * 4;

  float4 acc = {0.0f, 0.0f, 0.0f, 0.0f};
#pragma unroll
  for (int pt = 0; pt < 9; ++pt) {
    float4 wv = s_w[pt * 64 + px_l];
    int4 av = s_a[pt * 64 + px_l];
    float4 s00 = *(const float4*)(xb + av.x);
    float4 s01 = *(const float4*)(xb + av.y);
    float4 s10 = *(const float4*)(xb + av.z);
    float4 s11 = *(const float4*)(xb + av.w);
    acc.x = fmaf(wv.x, s00.x, acc.x); acc.y = fmaf(wv.x, s00.y, acc.y);
    acc.z = fmaf(wv.x, s00.z, acc.z); acc.w = fmaf(wv.x, s00.w, acc.w);
    acc.x = fmaf(wv.y, s01.x, acc.x); acc.y = fmaf(wv.y, s01.y, acc.y);
    acc.z = fmaf(wv.y, s01.z, acc.z); acc.w = fmaf(wv.y, s01.w, acc.w);
    acc.x = fmaf(wv.z, s10.x, acc.x); acc.y = fmaf(wv.z, s10.y, acc.y);
    acc.z = fmaf(wv.z, s10.z, acc.z); acc.w = fmaf(wv.z, s10.w, acc.w);
    acc.x = fmaf(wv.w, s11.x, acc.x); acc.y = fmaf(wv.w, s11.y, acc.y);
    acc.z = fmaf(wv.w, s11.z, acc.z); acc.w = fmaf(wv.w, s11.w, acc.w);
  }

  float* op = out + ((size_t)(n * C_ + g * GC_ + ch * 4)) * HW_ + p;
  op[0 * HW_] = acc.x;
  op[1 * HW_] = acc.y;
  op[2 * HW_] = acc.z;
  op[3 * HW_] = acc.w;
}

// ---------------------------------------------------------------------------
extern "C" void kernel_launch(void* const* d_in, const int* in_sizes, int n_in,
                              void* d_out, int out_size, void* d_ws, size_t ws_size,
                              hipStream_t stream) {
  const float* x    = (const float*)d_in[0];
  const float* dw_w = (const float*)d_in[1];
  const float* dw_b = (const float*)d_in[2];
  const float* gn_w = (const float*)d_in[3];
  const float* gn_b = (const float*)d_in[4];
  const float* om_w = (const float*)d_in[5];
  const float* om_b = (const float*)d_in[6];
  float* out = (float*)d_out;

  // workspace layout (~121 MB)
  float* xg = (float*)d_ws;                                  // 9437184 f  (37.7 MB)
  unsigned short* x1b = (unsigned short*)(xg + (size_t)N_ * CHW_);  // 9437184 us (18.9 MB)
  float* om = (float*)(x1b + (size_t)N_ * CHW_);             // 8*216*9216 f (63.7 MB)
  float* stats = om + (size_t)N_ * OM_ * HW_;                // 16 f
  float2* partials = (float2*)(stats + 16);                  // 36864 float2
  unsigned short* Abf = (unsigned short*)(partials + 36864); // 224*128 us

  k_stats_conv<<<(N_ * CHW_) / 256, 256, 0, stream>>>(x, dw_w, dw_b, partials);
  k_stats<<<N_, 256, 0, stream>>>(partials, stats);
  k_prep<<<(OMP_ * C_) / 256, 256, 0, stream>>>(om_w, Abf);
  k_transpose<<<dim3(HW_ / 32, C_ / 32, N_), dim3(32, 8), 0, stream>>>(x, xg);
  k_norm_gelu_t<<<dim3(HW_ / 32, C_ / 32, N_), dim3(32, 8), 0, stream>>>(
      x, dw_w, dw_b, stats, gn_w, gn_b, x1b);
  k_gemm_mfma<<<dim3(HW_ / 128, N_), 256, 0, stream>>>(x1b, Abf, om_b, om);
  k_sample<<<9216, 256, 0, stream>>>(xg, om, out);
}

// Round 6
// 238.080 us; speedup vs baseline: 5.9016x; 1.0738x over previous
//
#include <hip/hip_runtime.h>

#define N_   8
#define C_   128
#define H_   96
#define W_   96
#define G_   8
#define GC_  16
#define HW_  (H_ * W_)       // 9216
#define CHW_ (C_ * HW_)      // 1179648
#define OM_  216
#define OMP_ 224             // padded: 8 groups x 28 rows (27 live + 1 pad)
#define OMROWS2_ 112         // packed dword rows per sample (224/2)
#define EPS_ 1e-5f
#define BLKS_PER_N_ 1152     // k_front blocks per sample (288*4)

typedef short bf16x8 __attribute__((ext_vector_type(8)));
typedef float f32x4 __attribute__((ext_vector_type(4)));

static __device__ __forceinline__ unsigned short f2bf(float f) {
  unsigned int u = __float_as_uint(f);
  unsigned int r = (u + 0x7fffu + ((u >> 16) & 1u)) >> 16;
  return (unsigned short)r;
}
static __device__ __forceinline__ float lo_bf(unsigned int u) {
  return __uint_as_float(u << 16);
}
static __device__ __forceinline__ float hi_bf(unsigned int u) {
  return __uint_as_float(u & 0xffff0000u);
}

// ---------------------------------------------------------------------------
// K1 (fused): reads x once per element-role; computes depthwise conv for
// per-block sum/sumsq partials AND writes group-planar xg[n][g][hw][16].
// Grid (288, 4, 8), block (32,8): 32 px x 32 ch tile.
// ---------------------------------------------------------------------------
__global__ __launch_bounds__(256) void k_front(const float* __restrict__ x,
                                               const float* __restrict__ dw_w,
                                               const float* __restrict__ dw_b,
                                               float* __restrict__ xg,
                                               float2* __restrict__ partials) {
  __shared__ float tile[32][33];
  __shared__ float ls[4], lq[4];
  int tx = threadIdx.x;
  int ty = threadIdx.y;
  int p0 = blockIdx.x * 32;
  int c0 = blockIdx.y * 32;
  int n = blockIdx.z;
  int p = p0 + tx;
  int h = p / W_;
  int w = p - h * W_;

  float s = 0.0f, q = 0.0f;
#pragma unroll
  for (int i = 0; i < 4; ++i) {
    int c = c0 + ty + i * 8;
    const float* wp = dw_w + c * 9;
    const float* xp = x + (n * C_ + c) * HW_;
    float acc = dw_b[c];
    float center = 0.0f;
#pragma unroll
    for (int dy = 0; dy < 3; ++dy) {
#pragma unroll
      for (int dx = 0; dx < 3; ++dx) {
        int yy = h + dy - 1;
        int xx = w + dx - 1;
        bool v = (yy >= 0) & (yy < H_) & (xx >= 0) & (xx < W_);
        float xin = v ? xp[yy * W_ + xx] : 0.0f;
        if (dy == 1 && dx == 1) center = xin;
        acc = fmaf(xin, wp[dy * 3 + dx], acc);
      }
    }
    tile[ty + i * 8][tx] = center;
    s += acc;
    q += acc * acc;
  }

  int tid = ty * 32 + tx;
#pragma unroll
  for (int o = 32; o > 0; o >>= 1) {
    s += __shfl_down(s, o);
    q += __shfl_down(q, o);
  }
  int lane = tid & 63;
  int wv = tid >> 6;
  if (lane == 0) { ls[wv] = s; lq[wv] = q; }
  __syncthreads();
  if (tid == 0) {
    int bid = blockIdx.x + 288 * blockIdx.y + BLKS_PER_N_ * n;
    partials[bid] = make_float2(ls[0] + ls[1] + ls[2] + ls[3],
                                lq[0] + lq[1] + lq[2] + lq[3]);
  }

  int c = c0 + tx;
  int g = c >> 4;
  int cc = c & 15;
#pragma unroll
  for (int i = 0; i < 4; ++i) {
    int pp = p0 + ty + i * 8;
    xg[(((size_t)(n * G_ + g) * HW_) + pp) * GC_ + cc] = tile[tx][ty + i * 8];
  }
}

// ---------------------------------------------------------------------------
// K1b: reduce 1152 per-block partials per sample -> stats[n] = (sum, sumsq)
// ---------------------------------------------------------------------------
__global__ __launch_bounds__(256) void k_stats(const float2* __restrict__ partials,
                                               float* __restrict__ stats) {
  int n = blockIdx.x;
  int tid = threadIdx.x;
  const float2* p = partials + n * BLKS_PER_N_;
  float s = 0.0f, q = 0.0f;
  for (int i = tid; i < BLKS_PER_N_; i += 256) {
    float2 v = p[i];
    s += v.x;
    q += v.y;
  }
#pragma unroll
  for (int o = 32; o > 0; o >>= 1) {
    s += __shfl_down(s, o);
    q += __shfl_down(q, o);
  }
  __shared__ float ls[4], lq[4];
  int lane = tid & 63;
  int wv = tid >> 6;
  if (lane == 0) { ls[wv] = s; lq[wv] = q; }
  __syncthreads();
  if (tid == 0) {
    stats[n * 2 + 0] = ls[0] + ls[1] + ls[2] + ls[3];
    stats[n * 2 + 1] = lq[0] + lq[1] + lq[2] + lq[3];
  }
}

// ---------------------------------------------------------------------------
// K1c: permute+pad om_w -> A bf16 [224x128]: row o' = g*28+k holds om_w row
// g*27+k (k<27), zeros for k==27. Same permutation for bias (biasp).
// ---------------------------------------------------------------------------
__global__ __launch_bounds__(256) void k_prep(const float* __restrict__ om_w,
                                              const float* __restrict__ om_b,
                                              unsigned short* __restrict__ A,
                                              float* __restrict__ biasp) {
  int idx = blockIdx.x * 256 + threadIdx.x;   // 0 .. 224*128-1
  int o = idx >> 7;
  int cix = idx & 127;
  int g = o / 28;
  int k = o - g * 28;
  float v = (k < 27) ? om_w[(g * 27 + k) * C_ + cix] : 0.0f;
  A[idx] = f2bf(v);
  if (cix == 0) biasp[o] = (k < 27) ? om_b[g * 27 + k] : 0.0f;
}

// ---------------------------------------------------------------------------
// K3: recompute conv + layernorm + GELU + bf16 cast + transpose ->
// x1b NHWC bf16 [n][p][c]. Grid (288, 4, 8), block (32,8).
// ---------------------------------------------------------------------------
__global__ __launch_bounds__(256) void k_norm_gelu_t(const float* __restrict__ x,
                                                     const float* __restrict__ dw_w,
                                                     const float* __restrict__ dw_b,
                                                     const float* __restrict__ stats,
                                                     const float* __restrict__ gn_w,
                                                     const float* __restrict__ gn_b,
                                                     unsigned short* __restrict__ x1b) {
  __shared__ float tile[32][33];
  int tx = threadIdx.x;
  int ty = threadIdx.y;
  int p0 = blockIdx.x * 32;
  int c0 = blockIdx.y * 32;
  int n = blockIdx.z;

  float s = stats[n * 2 + 0];
  float q = stats[n * 2 + 1];
  const float inv = 1.0f / (float)CHW_;
  float mean = s * inv;
  float var = q * inv - mean * mean;
  float rstd = rsqrtf(var + EPS_);

  int p = p0 + tx;
  int h = p / W_;
  int w = p - h * W_;

#pragma unroll
  for (int i = 0; i < 4; ++i) {
    int c = c0 + ty + i * 8;
    const float* wp = dw_w + c * 9;
    const float* xp = x + (n * C_ + c) * HW_;
    float acc = dw_b[c];
#pragma unroll
    for (int dy = 0; dy < 3; ++dy) {
#pragma unroll
      for (int dx = 0; dx < 3; ++dx) {
        int yy = h + dy - 1;
        int xx = w + dx - 1;
        bool vok = (yy >= 0) & (yy < H_) & (xx >= 0) & (xx < W_);
        float xin = vok ? xp[yy * W_ + xx] : 0.0f;
        acc = fmaf(xin, wp[dy * 3 + dx], acc);
      }
    }
    float v = (acc - mean) * rstd * gn_w[c] + gn_b[c];
    float g = 0.5f * v * (1.0f + erff(v * 0.70710678118654752f));
    tile[ty + i * 8][tx] = g;
  }
  __syncthreads();
#pragma unroll
  for (int i = 0; i < 4; ++i) {
    int pp = p0 + ty + i * 8;
    x1b[((size_t)(n * HW_) + pp) * C_ + c0 + tx] = f2bf(tile[tx][ty + i * 8]);
  }
}

// ---------------------------------------------------------------------------
// K4: MFMA GEMM, bf16 in, f32 acc, bf16-PACKED out.
// om2[n][orow2][p] dword = (bf16 row 2*orow2) | (bf16 row 2*orow2+1)<<16.
// Block = 128-pixel slab x all 224 permuted o-rows. Grid (72, 8).
// ---------------------------------------------------------------------------
__global__ __launch_bounds__(256) void k_gemm_mfma(const unsigned short* __restrict__ Bt,
                                                   const unsigned short* __restrict__ A,
                                                   const float* __restrict__ biasp,
                                                   unsigned int* __restrict__ om2) {
  __shared__ unsigned short Bl[128 * 136];
  int tid = threadIdx.x;
  int pb = blockIdx.x;
  int n = blockIdx.y;
  int p0 = pb * 128;

  const unsigned short* src = Bt + ((size_t)n * HW_ + p0) * C_;
#pragma unroll
  for (int i = 0; i < 8; ++i) {
    int idx = i * 256 + tid;
    int row = idx >> 4;
    int col = idx & 15;
    *(uint4*)(&Bl[row * 136 + col * 8]) = *(const uint4*)(src + row * C_ + col * 8);
  }
  __syncthreads();

  int wave = tid >> 6;
  int lane = tid & 63;
  int quad = lane >> 4;
  int l16 = lane & 15;
  int pw = wave * 32;

  bf16x8 bfrag[2][4];
#pragma unroll
  for (int st = 0; st < 2; ++st) {
    int prow = pw + st * 16 + l16;
#pragma unroll
    for (int kk = 0; kk < 4; ++kk)
      bfrag[st][kk] = *(const bf16x8*)(&Bl[prow * 136 + kk * 32 + quad * 8]);
  }

  for (int ot = 0; ot < 14; ++ot) {
    const unsigned short* Ap = A + (ot * 16 + l16) * C_ + quad * 8;
    bf16x8 afrag[4];
#pragma unroll
    for (int kk = 0; kk < 4; ++kk)
      afrag[kk] = *(const bf16x8*)(Ap + kk * 32);

    f32x4 acc[2] = {{0.f, 0.f, 0.f, 0.f}, {0.f, 0.f, 0.f, 0.f}};
#pragma unroll
    for (int st = 0; st < 2; ++st)
#pragma unroll
      for (int kk = 0; kk < 4; ++kk)
        acc[st] = __builtin_amdgcn_mfma_f32_16x16x32_bf16(afrag[kk], bfrag[st][kk], acc[st], 0, 0, 0);

    int o0 = ot * 16 + quad * 4;               // even
    float4 bv = *(const float4*)(biasp + o0);
#pragma unroll
    for (int st = 0; st < 2; ++st) {
      int p = p0 + pw + st * 16 + l16;
      unsigned int pk0 = (unsigned int)f2bf(acc[st][0] + bv.x) |
                         ((unsigned int)f2bf(acc[st][1] + bv.y) << 16);
      unsigned int pk1 = (unsigned int)f2bf(acc[st][2] + bv.z) |
                         ((unsigned int)f2bf(acc[st][3] + bv.w) << 16);
      unsigned int* Cp = om2 + ((size_t)n * OMROWS2_ + (o0 >> 1)) * HW_ + p;
      Cp[0] = pk0;
      Cp[HW_] = pk1;
    }
  }
}

// ---------------------------------------------------------------------------
// K5: deformable bilinear sampling, two-phase; om now bf16-packed.
// Group g rows: packed row g*14 + pt -> (offx, offy); g*14 + 9 + (pt>>1)
// half (pt&1) -> mask.
// Grid: 9216 blocks = 8n (fastest, XCD-pinning) x 8g x 144 p-blocks.
// ---------------------------------------------------------------------------
__global__ __launch_bounds__(256) void k_sample(const float* __restrict__ xg,
                                                const unsigned int* __restrict__ om2,
                                                float* __restrict__ out) {
  __shared__ float4 s_w[9 * 64];
  __shared__ int4   s_a[9 * 64];

  int tid = threadIdx.x;
  int ord = blockIdx.x;
  int n = ord & 7;
  int t2 = ord >> 3;
  int g = t2 & 7;
  int pb = t2 >> 3;
  int p0 = pb * 64;

  const unsigned int* omb = om2 + ((size_t)n * OMROWS2_ + g * 14) * HW_ + p0;
  for (int j = tid; j < 576; j += 256) {
    int pt = j >> 6;
    int px = j & 63;
    int p = p0 + px;
    int h = p / W_;
    int w = p - h * W_;
    unsigned int od = omb[pt * HW_ + px];
    float offx = lo_bf(od);
    float offy = hi_bf(od);
    unsigned int md = omb[(9 + (pt >> 1)) * HW_ + px];
    float m = (pt & 1) ? hi_bf(md) : lo_bf(md);
    float locy = (float)(h + pt / 3 - 1) + offy;
    float locx = (float)(w + pt % 3 - 1) + offx;
    float y0f = floorf(locy);
    float x0f = floorf(locx);
    float ly = locy - y0f;
    float lx = locx - x0f;
    int y0 = (int)y0f;
    int x0 = (int)x0f;
    int y1 = y0 + 1;
    int x1 = x0 + 1;
    bool vy0 = (y0 >= 0) & (y0 < H_);
    bool vy1 = (y1 >= 0) & (y1 < H_);
    bool vx0 = (x0 >= 0) & (x0 < W_);
    bool vx1 = (x1 >= 0) & (x1 < W_);
    int yc0 = min(max(y0, 0), H_ - 1);
    int yc1 = min(max(y1, 0), H_ - 1);
    int xc0 = min(max(x0, 0), W_ - 1);
    int xc1 = min(max(x1, 0), W_ - 1);
    float t0 = (1.0f - ly) * m;
    float t1 = ly * m;
    float u0 = 1.0f - lx;
    float4 wv;
    wv.x = (vy0 & vx0) ? t0 * u0 : 0.0f;
    wv.y = (vy0 & vx1) ? t0 * lx : 0.0f;
    wv.z = (vy1 & vx0) ? t1 * u0 : 0.0f;
    wv.w = (vy1 & vx1) ? t1 * lx : 0.0f;
    int4 av;
    av.x = (yc0 * W_ + xc0) * GC_;
    av.y = (yc0 * W_ + xc1) * GC_;
    av.z = (yc1 * W_ + xc0) * GC_;
    av.w = (yc1 * W_ + xc1) * GC_;
    s_w[j] = wv;
    s_a[j] = av;
  }
  __syncthreads();

  int px_l = tid >> 2;
  int ch = tid & 3;
  int p = p0 + px_l;
  const float* xb = xg + ((size_t)(n * G_ + g) * HW_) * GC_ + ch * 4;

  float4 acc = {0.0f, 0.0f, 0.0f, 0.0f};
#pragma unroll
  for (int pt = 0; pt < 9; ++pt) {
    float4 wv = s_w[pt * 64 + px_l];
    int4 av = s_a[pt * 64 + px_l];
    float4 s00 = *(const float4*)(xb + av.x);
    float4 s01 = *(const float4*)(xb + av.y);
    float4 s10 = *(const float4*)(xb + av.z);
    float4 s11 = *(const float4*)(xb + av.w);
    acc.x = fmaf(wv.x, s00.x, acc.x); acc.y = fmaf(wv.x, s00.y, acc.y);
    acc.z = fmaf(wv.x, s00.z, acc.z); acc.w = fmaf(wv.x, s00.w, acc.w);
    acc.x = fmaf(wv.y, s01.x, acc.x); acc.y = fmaf(wv.y, s01.y, acc.y);
    acc.z = fmaf(wv.y, s01.z, acc.z); acc.w = fmaf(wv.y, s01.w, acc.w);
    acc.x = fmaf(wv.z, s10.x, acc.x); acc.y = fmaf(wv.z, s10.y, acc.y);
    acc.z = fmaf(wv.z, s10.z, acc.z); acc.w = fmaf(wv.z, s10.w, acc.w);
    acc.x = fmaf(wv.w, s11.x, acc.x); acc.y = fmaf(wv.w, s11.y, acc.y);
    acc.z = fmaf(wv.w, s11.z, acc.z); acc.w = fmaf(wv.w, s11.w, acc.w);
  }

  float* op = out + ((size_t)(n * C_ + g * GC_ + ch * 4)) * HW_ + p;
  op[0 * HW_] = acc.x;
  op[1 * HW_] = acc.y;
  op[2 * HW_] = acc.z;
  op[3 * HW_] = acc.w;
}

// ---------------------------------------------------------------------------
extern "C" void kernel_launch(void* const* d_in, const int* in_sizes, int n_in,
                              void* d_out, int out_size, void* d_ws, size_t ws_size,
                              hipStream_t stream) {
  const float* x    = (const float*)d_in[0];
  const float* dw_w = (const float*)d_in[1];
  const float* dw_b = (const float*)d_in[2];
  const float* gn_w = (const float*)d_in[3];
  const float* gn_b = (const float*)d_in[4];
  const float* om_w = (const float*)d_in[5];
  const float* om_b = (const float*)d_in[6];
  float* out = (float*)d_out;

  // workspace layout (~90 MB)
  float* xg = (float*)d_ws;                                        // 9437184 f
  unsigned short* x1b = (unsigned short*)(xg + (size_t)N_ * CHW_); // 9437184 us
  unsigned int* om2 = (unsigned int*)(x1b + (size_t)N_ * CHW_);    // 8*112*9216 u32
  float* stats = (float*)(om2 + (size_t)N_ * OMROWS2_ * HW_);      // 16 f
  float2* partials = (float2*)(stats + 16);                        // 9216 float2
  unsigned short* Abf = (unsigned short*)(partials + N_ * BLKS_PER_N_);
  float* biasp = (float*)(Abf + OMP_ * C_);                        // 224 f

  k_front<<<dim3(HW_ / 32, C_ / 32, N_), dim3(32, 8), 0, stream>>>(
      x, dw_w, dw_b, xg, partials);
  k_stats<<<N_, 256, 0, stream>>>(partials, stats);
  k_prep<<<(OMP_ * C_) / 256, 256, 0, stream>>>(om_w, om_b, Abf, biasp);
  k_norm_gelu_t<<<dim3(HW_ / 32, C_ / 32, N_), dim3(32, 8), 0, stream>>>(
      x, dw_w, dw_b, stats, gn_w, gn_b, x1b);
  k_gemm_mfma<<<dim3(HW_ / 128, N_), 256, 0, stream>>>(x1b, Abf, biasp, om2);
  k_sample<<<9216, 256, 0, stream>>>(xg, om2, out);
}

// Round 7
// 210.309 us; speedup vs baseline: 6.6809x; 1.1320x over previous
//
#include <hip/hip_runtime.h>

#define N_   8
#define C_   128
#define H_   96
#define W_   96
#define G_   8
#define GC_  16
#define HW_  (H_ * W_)       // 9216
#define CHW_ (C_ * HW_)      // 1179648
#define OM_  216
#define OMP_ 224             // padded: 8 groups x 28 rows (27 live + 1 pad)
#define OMROWS2_ 112         // packed dword rows per sample (224/2)
#define EPS_ 1e-5f
#define BLKS_PER_N_ 1152     // k_front blocks per sample (288*4)

typedef short bf16x8 __attribute__((ext_vector_type(8)));
typedef float f32x4 __attribute__((ext_vector_type(4)));

static __device__ __forceinline__ unsigned short f2bf(float f) {
  unsigned int u = __float_as_uint(f);
  unsigned int r = (u + 0x7fffu + ((u >> 16) & 1u)) >> 16;
  return (unsigned short)r;
}
static __device__ __forceinline__ float lo_bf(unsigned int u) {
  return __uint_as_float(u << 16);
}
static __device__ __forceinline__ float hi_bf(unsigned int u) {
  return __uint_as_float(u & 0xffff0000u);
}

// ---------------------------------------------------------------------------
// K1 (fused): single pass over x. Computes depthwise conv+bias (f32),
// emits: per-block sum/sumsq partials, conv output as bf16 NHWC (x1b,
// pre-norm), and group-planar raw x (xg) for the sampler.
// Grid (288, 4, 8), block (32,8): 32 px x 32 ch tile.
// ---------------------------------------------------------------------------
__global__ __launch_bounds__(256) void k_front(const float* __restrict__ x,
                                               const float* __restrict__ dw_w,
                                               const float* __restrict__ dw_b,
                                               float* __restrict__ xg,
                                               unsigned short* __restrict__ x1b,
                                               float2* __restrict__ partials) {
  __shared__ float tile_c[32][33];   // raw center values (for xg)
  __shared__ float tile_a[32][33];   // conv outputs (for x1b)
  __shared__ float ls[4], lq[4];
  int tx = threadIdx.x;
  int ty = threadIdx.y;
  int p0 = blockIdx.x * 32;
  int c0 = blockIdx.y * 32;
  int n = blockIdx.z;
  int p = p0 + tx;
  int h = p / W_;
  int w = p - h * W_;

  float s = 0.0f, q = 0.0f;
#pragma unroll
  for (int i = 0; i < 4; ++i) {
    int c = c0 + ty + i * 8;
    const float* wp = dw_w + c * 9;
    const float* xp = x + (n * C_ + c) * HW_;
    float acc = dw_b[c];
    float center = 0.0f;
#pragma unroll
    for (int dy = 0; dy < 3; ++dy) {
#pragma unroll
      for (int dx = 0; dx < 3; ++dx) {
        int yy = h + dy - 1;
        int xx = w + dx - 1;
        bool v = (yy >= 0) & (yy < H_) & (xx >= 0) & (xx < W_);
        float xin = v ? xp[yy * W_ + xx] : 0.0f;
        if (dy == 1 && dx == 1) center = xin;
        acc = fmaf(xin, wp[dy * 3 + dx], acc);
      }
    }
    tile_c[ty + i * 8][tx] = center;
    tile_a[ty + i * 8][tx] = acc;
    s += acc;
    q += acc * acc;
  }

  int tid = ty * 32 + tx;
#pragma unroll
  for (int o = 32; o > 0; o >>= 1) {
    s += __shfl_down(s, o);
    q += __shfl_down(q, o);
  }
  int lane = tid & 63;
  int wv = tid >> 6;
  if (lane == 0) { ls[wv] = s; lq[wv] = q; }
  __syncthreads();
  if (tid == 0) {
    int bid = blockIdx.x + 288 * blockIdx.y + BLKS_PER_N_ * n;
    partials[bid] = make_float2(ls[0] + ls[1] + ls[2] + ls[3],
                                lq[0] + lq[1] + lq[2] + lq[3]);
  }

  int c = c0 + tx;
  int g = c >> 4;
  int cc = c & 15;
#pragma unroll
  for (int i = 0; i < 4; ++i) {
    int pp = p0 + ty + i * 8;
    xg[(((size_t)(n * G_ + g) * HW_) + pp) * GC_ + cc] = tile_c[tx][ty + i * 8];
    x1b[((size_t)(n * HW_) + pp) * C_ + c] = f2bf(tile_a[tx][ty + i * 8]);
  }
}

// ---------------------------------------------------------------------------
// K1b: reduce 1152 per-block partials per sample -> stats[n] = (sum, sumsq)
// ---------------------------------------------------------------------------
__global__ __launch_bounds__(256) void k_stats(const float2* __restrict__ partials,
                                               float* __restrict__ stats) {
  int n = blockIdx.x;
  int tid = threadIdx.x;
  const float2* p = partials + n * BLKS_PER_N_;
  float s = 0.0f, q = 0.0f;
  for (int i = tid; i < BLKS_PER_N_; i += 256) {
    float2 v = p[i];
    s += v.x;
    q += v.y;
  }
#pragma unroll
  for (int o = 32; o > 0; o >>= 1) {
    s += __shfl_down(s, o);
    q += __shfl_down(q, o);
  }
  __shared__ float ls[4], lq[4];
  int lane = tid & 63;
  int wv = tid >> 6;
  if (lane == 0) { ls[wv] = s; lq[wv] = q; }
  __syncthreads();
  if (tid == 0) {
    stats[n * 2 + 0] = ls[0] + ls[1] + ls[2] + ls[3];
    stats[n * 2 + 1] = lq[0] + lq[1] + lq[2] + lq[3];
  }
}

// ---------------------------------------------------------------------------
// K1c: permute+pad om_w -> A bf16 [224x128]: row o' = g*28+k holds om_w row
// g*27+k (k<27), zeros for k==27. Same permutation for bias (biasp).
// ---------------------------------------------------------------------------
__global__ __launch_bounds__(256) void k_prep(const float* __restrict__ om_w,
                                              const float* __restrict__ om_b,
                                              unsigned short* __restrict__ A,
                                              float* __restrict__ biasp) {
  int idx = blockIdx.x * 256 + threadIdx.x;   // 0 .. 224*128-1
  int o = idx >> 7;
  int cix = idx & 127;
  int g = o / 28;
  int k = o - g * 28;
  float v = (k < 27) ? om_w[(g * 27 + k) * C_ + cix] : 0.0f;
  A[idx] = f2bf(v);
  if (cix == 0) biasp[o] = (k < 27) ? om_b[g * 27 + k] : 0.0f;
}

// ---------------------------------------------------------------------------
// K4: MFMA GEMM with fused layernorm+GELU on the B operand.
// B source = x1b (conv bf16, pre-norm). During global->LDS staging each
// element gets z = a_c*v + b_c (a=rstd*gn_w, b=gn_b-mean*rstd*gn_w) then
// exact-erf GELU, repacked bf16. Staging column (tid&15) is constant per
// thread -> each thread's 8 channels' a/b live in registers.
// Output om2 bf16-packed (2 o-rows per dword). Grid (72, 8).
// ---------------------------------------------------------------------------
__global__ __launch_bounds__(256) void k_gemm_mfma(const unsigned short* __restrict__ Bt,
                                                   const unsigned short* __restrict__ A,
                                                   const float* __restrict__ biasp,
                                                   const float* __restrict__ stats,
                                                   const float* __restrict__ gn_w,
                                                   const float* __restrict__ gn_b,
                                                   unsigned int* __restrict__ om2) {
  __shared__ unsigned short Bl[128 * 136];
  int tid = threadIdx.x;
  int pb = blockIdx.x;
  int n = blockIdx.y;
  int p0 = pb * 128;

  // per-sample affine for this thread's 8 staging channels
  float sum = stats[n * 2 + 0];
  float ssq = stats[n * 2 + 1];
  const float inv = 1.0f / (float)CHW_;
  float mean = sum * inv;
  float var = ssq * inv - mean * mean;
  float rstd = rsqrtf(var + EPS_);
  int cbase = (tid & 15) * 8;
  float a8[8], b8[8];
#pragma unroll
  for (int j = 0; j < 8; ++j) {
    float gw = gn_w[cbase + j];
    float gb = gn_b[cbase + j];
    a8[j] = rstd * gw;
    b8[j] = gb - mean * rstd * gw;
  }

  const unsigned short* src = Bt + ((size_t)n * HW_ + p0) * C_;
#pragma unroll
  for (int i = 0; i < 8; ++i) {
    int idx = i * 256 + tid;
    int row = idx >> 4;
    int col = idx & 15;                 // == tid & 15
    uint4 raw = *(const uint4*)(src + row * C_ + col * 8);
    unsigned int d[4] = {raw.x, raw.y, raw.z, raw.w};
    unsigned int od[4];
#pragma unroll
    for (int t = 0; t < 4; ++t) {
      float v0 = lo_bf(d[t]);
      float v1 = hi_bf(d[t]);
      float z0 = fmaf(v0, a8[2 * t], b8[2 * t]);
      float z1 = fmaf(v1, a8[2 * t + 1], b8[2 * t + 1]);
      float g0 = 0.5f * z0 * (1.0f + erff(z0 * 0.70710678118654752f));
      float g1 = 0.5f * z1 * (1.0f + erff(z1 * 0.70710678118654752f));
      od[t] = (unsigned int)f2bf(g0) | ((unsigned int)f2bf(g1) << 16);
    }
    uint4 packed = {od[0], od[1], od[2], od[3]};
    *(uint4*)(&Bl[row * 136 + col * 8]) = packed;
  }
  __syncthreads();

  int wave = tid >> 6;
  int lane = tid & 63;
  int quad = lane >> 4;
  int l16 = lane & 15;
  int pw = wave * 32;

  bf16x8 bfrag[2][4];
#pragma unroll
  for (int st = 0; st < 2; ++st) {
    int prow = pw + st * 16 + l16;
#pragma unroll
    for (int kk = 0; kk < 4; ++kk)
      bfrag[st][kk] = *(const bf16x8*)(&Bl[prow * 136 + kk * 32 + quad * 8]);
  }

  for (int ot = 0; ot < 14; ++ot) {
    const unsigned short* Ap = A + (ot * 16 + l16) * C_ + quad * 8;
    bf16x8 afrag[4];
#pragma unroll
    for (int kk = 0; kk < 4; ++kk)
      afrag[kk] = *(const bf16x8*)(Ap + kk * 32);

    f32x4 acc[2] = {{0.f, 0.f, 0.f, 0.f}, {0.f, 0.f, 0.f, 0.f}};
#pragma unroll
    for (int st = 0; st < 2; ++st)
#pragma unroll
      for (int kk = 0; kk < 4; ++kk)
        acc[st] = __builtin_amdgcn_mfma_f32_16x16x32_bf16(afrag[kk], bfrag[st][kk], acc[st], 0, 0, 0);

    int o0 = ot * 16 + quad * 4;               // even
    float4 bv = *(const float4*)(biasp + o0);
#pragma unroll
    for (int st = 0; st < 2; ++st) {
      int p = p0 + pw + st * 16 + l16;
      unsigned int pk0 = (unsigned int)f2bf(acc[st][0] + bv.x) |
                         ((unsigned int)f2bf(acc[st][1] + bv.y) << 16);
      unsigned int pk1 = (unsigned int)f2bf(acc[st][2] + bv.z) |
                         ((unsigned int)f2bf(acc[st][3] + bv.w) << 16);
      unsigned int* Cp = om2 + ((size_t)n * OMROWS2_ + (o0 >> 1)) * HW_ + p;
      Cp[0] = pk0;
      Cp[HW_] = pk1;
    }
  }
}

// ---------------------------------------------------------------------------
// K5: deformable bilinear sampling, two-phase; om bf16-packed.
// Grid: 9216 blocks = 8n (fastest, XCD-pinning) x 8g x 144 p-blocks.
// ---------------------------------------------------------------------------
__global__ __launch_bounds__(256) void k_sample(const float* __restrict__ xg,
                                                const unsigned int* __restrict__ om2,
                                                float* __restrict__ out) {
  __shared__ float4 s_w[9 * 64];
  __shared__ int4   s_a[9 * 64];

  int tid = threadIdx.x;
  int ord = blockIdx.x;
  int n = ord & 7;
  int t2 = ord >> 3;
  int g = t2 & 7;
  int pb = t2 >> 3;
  int p0 = pb * 64;

  const unsigned int* omb = om2 + ((size_t)n * OMROWS2_ + g * 14) * HW_ + p0;
  for (int j = tid; j < 576; j += 256) {
    int pt = j >> 6;
    int px = j & 63;
    int p = p0 + px;
    int h = p / W_;
    int w = p - h * W_;
    unsigned int od = omb[pt * HW_ + px];
    float offx = lo_bf(od);
    float offy = hi_bf(od);
    unsigned int md = omb[(9 + (pt >> 1)) * HW_ + px];
    float m = (pt & 1) ? hi_bf(md) : lo_bf(md);
    float locy = (float)(h + pt / 3 - 1) + offy;
    float locx = (float)(w + pt % 3 - 1) + offx;
    float y0f = floorf(locy);
    float x0f = floorf(locx);
    float ly = locy - y0f;
    float lx = locx - x0f;
    int y0 = (int)y0f;
    int x0 = (int)x0f;
    int y1 = y0 + 1;
    int x1 = x0 + 1;
    bool vy0 = (y0 >= 0) & (y0 < H_);
    bool vy1 = (y1 >= 0) & (y1 < H_);
    bool vx0 = (x0 >= 0) & (x0 < W_);
    bool vx1 = (x1 >= 0) & (x1 < W_);
    int yc0 = min(max(y0, 0), H_ - 1);
    int yc1 = min(max(y1, 0), H_ - 1);
    int xc0 = min(max(x0, 0), W_ - 1);
    int xc1 = min(max(x1, 0), W_ - 1);
    float t0 = (1.0f - ly) * m;
    float t1 = ly * m;
    float u0 = 1.0f - lx;
    float4 wv;
    wv.x = (vy0 & vx0) ? t0 * u0 : 0.0f;
    wv.y = (vy0 & vx1) ? t0 * lx : 0.0f;
    wv.z = (vy1 & vx0) ? t1 * u0 : 0.0f;
    wv.w = (vy1 & vx1) ? t1 * lx : 0.0f;
    int4 av;
    av.x = (yc0 * W_ + xc0) * GC_;
    av.y = (yc0 * W_ + xc1) * GC_;
    av.z = (yc1 * W_ + xc0) * GC_;
    av.w = (yc1 * W_ + xc1) * GC_;
    s_w[j] = wv;
    s_a[j] = av;
  }
  __syncthreads();

  int px_l = tid >> 2;
  int ch = tid & 3;
  int p = p0 + px_l;
  const float* xb = xg + ((size_t)(n * G_ + g) * HW_) * GC_ + ch * 4;

  float4 acc = {0.0f, 0.0f, 0.0f, 0.0f};
#pragma unroll
  for (int pt = 0; pt < 9; ++pt) {
    float4 wv = s_w[pt * 64 + px_l];
    int4 av = s_a[pt * 64 + px_l];
    float4 s00 = *(const float4*)(xb + av.x);
    float4 s01 = *(const float4*)(xb + av.y);
    float4 s10 = *(const float4*)(xb + av.z);
    float4 s11 = *(const float4*)(xb + av.w);
    acc.x = fmaf(wv.x, s00.x, acc.x); acc.y = fmaf(wv.x, s00.y, acc.y);
    acc.z = fmaf(wv.x, s00.z, acc.z); acc.w = fmaf(wv.x, s00.w, acc.w);
    acc.x = fmaf(wv.y, s01.x, acc.x); acc.y = fmaf(wv.y, s01.y, acc.y);
    acc.z = fmaf(wv.y, s01.z, acc.z); acc.w = fmaf(wv.y, s01.w, acc.w);
    acc.x = fmaf(wv.z, s10.x, acc.x); acc.y = fmaf(wv.z, s10.y, acc.y);
    acc.z = fmaf(wv.z, s10.z, acc.z); acc.w = fmaf(wv.z, s10.w, acc.w);
    acc.x = fmaf(wv.w, s11.x, acc.x); acc.y = fmaf(wv.w, s11.y, acc.y);
    acc.z = fmaf(wv.w, s11.z, acc.z); acc.w = fmaf(wv.w, s11.w, acc.w);
  }

  float* op = out + ((size_t)(n * C_ + g * GC_ + ch * 4)) * HW_ + p;
  op[0 * HW_] = acc.x;
  op[1 * HW_] = acc.y;
  op[2 * HW_] = acc.z;
  op[3 * HW_] = acc.w;
}

// ---------------------------------------------------------------------------
extern "C" void kernel_launch(void* const* d_in, const int* in_sizes, int n_in,
                              void* d_out, int out_size, void* d_ws, size_t ws_size,
                              hipStream_t stream) {
  const float* x    = (const float*)d_in[0];
  const float* dw_w = (const float*)d_in[1];
  const float* dw_b = (const float*)d_in[2];
  const float* gn_w = (const float*)d_in[3];
  const float* gn_b = (const float*)d_in[4];
  const float* om_w = (const float*)d_in[5];
  const float* om_b = (const float*)d_in[6];
  float* out = (float*)d_out;

  // workspace layout (~90 MB)
  float* xg = (float*)d_ws;                                        // 9437184 f
  unsigned short* x1b = (unsigned short*)(xg + (size_t)N_ * CHW_); // 9437184 us
  unsigned int* om2 = (unsigned int*)(x1b + (size_t)N_ * CHW_);    // 8*112*9216 u32
  float* stats = (float*)(om2 + (size_t)N_ * OMROWS2_ * HW_);      // 16 f
  float2* partials = (float2*)(stats + 16);                        // 9216 float2
  unsigned short* Abf = (unsigned short*)(partials + N_ * BLKS_PER_N_);
  float* biasp = (float*)(Abf + OMP_ * C_);                        // 224 f

  k_front<<<dim3(HW_ / 32, C_ / 32, N_), dim3(32, 8), 0, stream>>>(
      x, dw_w, dw_b, xg, x1b, partials);
  k_stats<<<N_, 256, 0, stream>>>(partials, stats);
  k_prep<<<(OMP_ * C_) / 256, 256, 0, stream>>>(om_w, om_b, Abf, biasp);
  k_gemm_mfma<<<dim3(HW_ / 128, N_), 256, 0, stream>>>(
      x1b, Abf, biasp, stats, gn_w, gn_b, om2);
  k_sample<<<9216, 256, 0, stream>>>(xg, om2, out);
}

// Round 8
// 204.645 us; speedup vs baseline: 6.8659x; 1.0277x over previous
//
#include <hip/hip_runtime.h>

#define N_   8
#define C_   128
#define H_   96
#define W_   96
#define G_   8
#define GC_  16
#define HW_  (H_ * W_)       // 9216
#define CHW_ (C_ * HW_)      // 1179648
#define OM_  216
#define OMP_ 224             // padded: 8 groups x 28 rows (27 live + 1 pad)
#define OMROWS2_ 112         // packed dword rows per sample (224/2)
#define EPS_ 1e-5f
#define BLKS_PER_N_ 1152     // k_front blocks per sample (288*4)

typedef short bf16x8 __attribute__((ext_vector_type(8)));
typedef float f32x4 __attribute__((ext_vector_type(4)));

static __device__ __forceinline__ unsigned short f2bf(float f) {
  unsigned int u = __float_as_uint(f);
  unsigned int r = (u + 0x7fffu + ((u >> 16) & 1u)) >> 16;
  return (unsigned short)r;
}
static __device__ __forceinline__ float lo_bf(unsigned int u) {
  return __uint_as_float(u << 16);
}
static __device__ __forceinline__ float hi_bf(unsigned int u) {
  return __uint_as_float(u & 0xffff0000u);
}

// ---------------------------------------------------------------------------
// K1 (fused): single pass over x. Computes depthwise conv+bias (f32),
// emits: per-block sum/sumsq partials, conv output as bf16 NHWC (x1b,
// pre-norm), and group-planar raw x as bf16 (xgb) for the sampler.
// Grid (288, 4, 8), block (32,8): 32 px x 32 ch tile.
// ---------------------------------------------------------------------------
__global__ __launch_bounds__(256) void k_front(const float* __restrict__ x,
                                               const float* __restrict__ dw_w,
                                               const float* __restrict__ dw_b,
                                               unsigned short* __restrict__ xgb,
                                               unsigned short* __restrict__ x1b,
                                               float2* __restrict__ partials) {
  __shared__ float tile_c[32][33];   // raw center values (for xgb)
  __shared__ float tile_a[32][33];   // conv outputs (for x1b)
  __shared__ float ls[4], lq[4];
  int tx = threadIdx.x;
  int ty = threadIdx.y;
  int p0 = blockIdx.x * 32;
  int c0 = blockIdx.y * 32;
  int n = blockIdx.z;
  int p = p0 + tx;
  int h = p / W_;
  int w = p - h * W_;

  float s = 0.0f, q = 0.0f;
#pragma unroll
  for (int i = 0; i < 4; ++i) {
    int c = c0 + ty + i * 8;
    const float* wp = dw_w + c * 9;
    const float* xp = x + (n * C_ + c) * HW_;
    float acc = dw_b[c];
    float center = 0.0f;
#pragma unroll
    for (int dy = 0; dy < 3; ++dy) {
#pragma unroll
      for (int dx = 0; dx < 3; ++dx) {
        int yy = h + dy - 1;
        int xx = w + dx - 1;
        bool v = (yy >= 0) & (yy < H_) & (xx >= 0) & (xx < W_);
        float xin = v ? xp[yy * W_ + xx] : 0.0f;
        if (dy == 1 && dx == 1) center = xin;
        acc = fmaf(xin, wp[dy * 3 + dx], acc);
      }
    }
    tile_c[ty + i * 8][tx] = center;
    tile_a[ty + i * 8][tx] = acc;
    s += acc;
    q += acc * acc;
  }

  int tid = ty * 32 + tx;
#pragma unroll
  for (int o = 32; o > 0; o >>= 1) {
    s += __shfl_down(s, o);
    q += __shfl_down(q, o);
  }
  int lane = tid & 63;
  int wv = tid >> 6;
  if (lane == 0) { ls[wv] = s; lq[wv] = q; }
  __syncthreads();
  if (tid == 0) {
    int bid = blockIdx.x + 288 * blockIdx.y + BLKS_PER_N_ * n;
    partials[bid] = make_float2(ls[0] + ls[1] + ls[2] + ls[3],
                                lq[0] + lq[1] + lq[2] + lq[3]);
  }

  int c = c0 + tx;
  int g = c >> 4;
  int cc = c & 15;
#pragma unroll
  for (int i = 0; i < 4; ++i) {
    int pp = p0 + ty + i * 8;
    xgb[(((size_t)(n * G_ + g) * HW_) + pp) * GC_ + cc] = f2bf(tile_c[tx][ty + i * 8]);
    x1b[((size_t)(n * HW_) + pp) * C_ + c] = f2bf(tile_a[tx][ty + i * 8]);
  }
}

// ---------------------------------------------------------------------------
// K1b: reduce 1152 per-block partials per sample -> stats[n] = (sum, sumsq)
// ---------------------------------------------------------------------------
__global__ __launch_bounds__(256) void k_stats(const float2* __restrict__ partials,
                                               float* __restrict__ stats) {
  int n = blockIdx.x;
  int tid = threadIdx.x;
  const float2* p = partials + n * BLKS_PER_N_;
  float s = 0.0f, q = 0.0f;
  for (int i = tid; i < BLKS_PER_N_; i += 256) {
    float2 v = p[i];
    s += v.x;
    q += v.y;
  }
#pragma unroll
  for (int o = 32; o > 0; o >>= 1) {
    s += __shfl_down(s, o);
    q += __shfl_down(q, o);
  }
  __shared__ float ls[4], lq[4];
  int lane = tid & 63;
  int wv = tid >> 6;
  if (lane == 0) { ls[wv] = s; lq[wv] = q; }
  __syncthreads();
  if (tid == 0) {
    stats[n * 2 + 0] = ls[0] + ls[1] + ls[2] + ls[3];
    stats[n * 2 + 1] = lq[0] + lq[1] + lq[2] + lq[3];
  }
}

// ---------------------------------------------------------------------------
// K1c: permute+pad om_w -> A bf16 [224x128]: row o' = g*28+k holds om_w row
// g*27+k (k<27), zeros for k==27. Same permutation for bias (biasp).
// ---------------------------------------------------------------------------
__global__ __launch_bounds__(256) void k_prep(const float* __restrict__ om_w,
                                              const float* __restrict__ om_b,
                                              unsigned short* __restrict__ A,
                                              float* __restrict__ biasp) {
  int idx = blockIdx.x * 256 + threadIdx.x;   // 0 .. 224*128-1
  int o = idx >> 7;
  int cix = idx & 127;
  int g = o / 28;
  int k = o - g * 28;
  float v = (k < 27) ? om_w[(g * 27 + k) * C_ + cix] : 0.0f;
  A[idx] = f2bf(v);
  if (cix == 0) biasp[o] = (k < 27) ? om_b[g * 27 + k] : 0.0f;
}

// ---------------------------------------------------------------------------
// K4: MFMA GEMM with fused layernorm+GELU on the B operand (as R7).
// Output om2 bf16-packed (2 o-rows per dword). Grid (72, 8).
// ---------------------------------------------------------------------------
__global__ __launch_bounds__(256) void k_gemm_mfma(const unsigned short* __restrict__ Bt,
                                                   const unsigned short* __restrict__ A,
                                                   const float* __restrict__ biasp,
                                                   const float* __restrict__ stats,
                                                   const float* __restrict__ gn_w,
                                                   const float* __restrict__ gn_b,
                                                   unsigned int* __restrict__ om2) {
  __shared__ unsigned short Bl[128 * 136];
  int tid = threadIdx.x;
  int pb = blockIdx.x;
  int n = blockIdx.y;
  int p0 = pb * 128;

  float sum = stats[n * 2 + 0];
  float ssq = stats[n * 2 + 1];
  const float inv = 1.0f / (float)CHW_;
  float mean = sum * inv;
  float var = ssq * inv - mean * mean;
  float rstd = rsqrtf(var + EPS_);
  int cbase = (tid & 15) * 8;
  float a8[8], b8[8];
#pragma unroll
  for (int j = 0; j < 8; ++j) {
    float gw = gn_w[cbase + j];
    float gb = gn_b[cbase + j];
    a8[j] = rstd * gw;
    b8[j] = gb - mean * rstd * gw;
  }

  const unsigned short* src = Bt + ((size_t)n * HW_ + p0) * C_;
#pragma unroll
  for (int i = 0; i < 8; ++i) {
    int idx = i * 256 + tid;
    int row = idx >> 4;
    int col = idx & 15;                 // == tid & 15
    uint4 raw = *(const uint4*)(src + row * C_ + col * 8);
    unsigned int d[4] = {raw.x, raw.y, raw.z, raw.w};
    unsigned int od[4];
#pragma unroll
    for (int t = 0; t < 4; ++t) {
      float v0 = lo_bf(d[t]);
      float v1 = hi_bf(d[t]);
      float z0 = fmaf(v0, a8[2 * t], b8[2 * t]);
      float z1 = fmaf(v1, a8[2 * t + 1], b8[2 * t + 1]);
      float g0 = 0.5f * z0 * (1.0f + erff(z0 * 0.70710678118654752f));
      float g1 = 0.5f * z1 * (1.0f + erff(z1 * 0.70710678118654752f));
      od[t] = (unsigned int)f2bf(g0) | ((unsigned int)f2bf(g1) << 16);
    }
    uint4 packed = {od[0], od[1], od[2], od[3]};
    *(uint4*)(&Bl[row * 136 + col * 8]) = packed;
  }
  __syncthreads();

  int wave = tid >> 6;
  int lane = tid & 63;
  int quad = lane >> 4;
  int l16 = lane & 15;
  int pw = wave * 32;

  bf16x8 bfrag[2][4];
#pragma unroll
  for (int st = 0; st < 2; ++st) {
    int prow = pw + st * 16 + l16;
#pragma unroll
    for (int kk = 0; kk < 4; ++kk)
      bfrag[st][kk] = *(const bf16x8*)(&Bl[prow * 136 + kk * 32 + quad * 8]);
  }

  for (int ot = 0; ot < 14; ++ot) {
    const unsigned short* Ap = A + (ot * 16 + l16) * C_ + quad * 8;
    bf16x8 afrag[4];
#pragma unroll
    for (int kk = 0; kk < 4; ++kk)
      afrag[kk] = *(const bf16x8*)(Ap + kk * 32);

    f32x4 acc[2] = {{0.f, 0.f, 0.f, 0.f}, {0.f, 0.f, 0.f, 0.f}};
#pragma unroll
    for (int st = 0; st < 2; ++st)
#pragma unroll
      for (int kk = 0; kk < 4; ++kk)
        acc[st] = __builtin_amdgcn_mfma_f32_16x16x32_bf16(afrag[kk], bfrag[st][kk], acc[st], 0, 0, 0);

    int o0 = ot * 16 + quad * 4;               // even
    float4 bv = *(const float4*)(biasp + o0);
#pragma unroll
    for (int st = 0; st < 2; ++st) {
      int p = p0 + pw + st * 16 + l16;
      unsigned int pk0 = (unsigned int)f2bf(acc[st][0] + bv.x) |
                         ((unsigned int)f2bf(acc[st][1] + bv.y) << 16);
      unsigned int pk1 = (unsigned int)f2bf(acc[st][2] + bv.z) |
                         ((unsigned int)f2bf(acc[st][3] + bv.w) << 16);
      unsigned int* Cp = om2 + ((size_t)n * OMROWS2_ + (o0 >> 1)) * HW_ + p;
      Cp[0] = pk0;
      Cp[HW_] = pk1;
    }
  }
}

// ---------------------------------------------------------------------------
// K5: deformable bilinear sampling from bf16 group-planar xgb.
// Phase 1 (576 jobs): per (pt,px) redistribute the 4 bilinear corner weights
// onto the two physical rows xs, xs+1 (xs = clamp(x0,0,W-2)) so clamped /
// invalid corners are exact; emit 4 row-weights + 2 row-pair base offsets.
// Phase 2: 4 lanes/px; each pt needs 2 dwordx4 loads (y0-rowpair, y1-rowpair,
// 64 B span covers both x-corners, all 16 ch). Final __shfl_xor(2) folds the
// two row halves. Grid: 9216 blocks = 8n x 8g x 144 p-blocks.
// ---------------------------------------------------------------------------
__global__ __launch_bounds__(256) void k_sample(const unsigned short* __restrict__ xgb,
                                                const unsigned int* __restrict__ om2,
                                                float* __restrict__ out) {
  __shared__ float4 s_w[9 * 64];   // (wy0r0, wy0r1, wy1r0, wy1r1)
  __shared__ int2   s_a[9 * 64];   // element offsets of y0/y1 row-pairs

  int tid = threadIdx.x;
  int ord = blockIdx.x;
  int n = ord & 7;
  int t2 = ord >> 3;
  int g = t2 & 7;
  int pb = t2 >> 3;
  int p0 = pb * 64;

  const unsigned int* omb = om2 + ((size_t)n * OMROWS2_ + g * 14) * HW_ + p0;
  for (int j = tid; j < 576; j += 256) {
    int pt = j >> 6;
    int px = j & 63;
    int p = p0 + px;
    int h = p / W_;
    int w = p - h * W_;
    unsigned int od = omb[pt * HW_ + px];
    float offx = lo_bf(od);
    float offy = hi_bf(od);
    unsigned int md = omb[(9 + (pt >> 1)) * HW_ + px];
    float m = (pt & 1) ? hi_bf(md) : lo_bf(md);
    float locy = (float)(h + pt / 3 - 1) + offy;
    float locx = (float)(w + pt % 3 - 1) + offx;
    float y0f = floorf(locy);
    float x0f = floorf(locx);
    float ly = locy - y0f;
    float lx = locx - x0f;
    int y0 = (int)y0f;
    int x0 = (int)x0f;
    int y1 = y0 + 1;
    int x1 = x0 + 1;
    bool vy0 = (y0 >= 0) & (y0 < H_);
    bool vy1 = (y1 >= 0) & (y1 < H_);
    bool vx0 = (x0 >= 0) & (x0 < W_);
    bool vx1 = (x1 >= 0) & (x1 < W_);
    float t0 = (1.0f - ly) * m;
    float t1 = ly * m;
    float u0 = 1.0f - lx;
    float w00 = (vy0 & vx0) ? t0 * u0 : 0.0f;
    float w01 = (vy0 & vx1) ? t0 * lx : 0.0f;
    float w10 = (vy1 & vx0) ? t1 * u0 : 0.0f;
    float w11 = (vy1 & vx1) ? t1 * lx : 0.0f;
    int yc0 = min(max(y0, 0), H_ - 1);
    int yc1 = min(max(y1, 0), H_ - 1);
    int xs  = min(max(x0, 0), W_ - 2);
    int idx0 = min(max(x0, 0), W_ - 1) - xs;       // 0 or 1
    int idx1 = min(max(x1, 0), W_ - 1) - xs;       // 0 or 1
    float4 wv;
    wv.x = (idx0 == 0 ? w00 : 0.0f) + (idx1 == 0 ? w01 : 0.0f);
    wv.y = (idx0 == 1 ? w00 : 0.0f) + (idx1 == 1 ? w01 : 0.0f);
    wv.z = (idx0 == 0 ? w10 : 0.0f) + (idx1 == 0 ? w11 : 0.0f);
    wv.w = (idx0 == 1 ? w10 : 0.0f) + (idx1 == 1 ? w11 : 0.0f);
    int2 av;
    av.x = (yc0 * W_ + xs) * GC_;
    av.y = (yc1 * W_ + xs) * GC_;
    s_w[j] = wv;
    s_a[j] = av;
  }
  __syncthreads();

  int px_l = tid >> 2;             // 0..63
  int sub = tid & 3;               // (rowhalf, chunk): sub = rowhalf*2+chunk? no: chunk = sub&1 within row
  int rowhalf = sub >> 1;
  int chunk = sub & 1;
  int p = p0 + px_l;
  const unsigned short* xbb = xgb + ((size_t)(n * G_ + g) * HW_) * GC_;

  float acc[8] = {0, 0, 0, 0, 0, 0, 0, 0};
#pragma unroll
  for (int pt = 0; pt < 9; ++pt) {
    float4 wv = s_w[pt * 64 + px_l];
    int2 av = s_a[pt * 64 + px_l];
    float w0 = rowhalf ? wv.y : wv.x;
    float w1 = rowhalf ? wv.w : wv.z;
    uint4 r0 = *(const uint4*)(xbb + av.x + sub * 8);
    uint4 r1 = *(const uint4*)(xbb + av.y + sub * 8);
    unsigned int d0[4] = {r0.x, r0.y, r0.z, r0.w};
    unsigned int d1[4] = {r1.x, r1.y, r1.z, r1.w};
#pragma unroll
    for (int t = 0; t < 4; ++t) {
      acc[2 * t]     = fmaf(w0, lo_bf(d0[t]), acc[2 * t]);
      acc[2 * t + 1] = fmaf(w0, hi_bf(d0[t]), acc[2 * t + 1]);
    }
#pragma unroll
    for (int t = 0; t < 4; ++t) {
      acc[2 * t]     = fmaf(w1, lo_bf(d1[t]), acc[2 * t]);
      acc[2 * t + 1] = fmaf(w1, hi_bf(d1[t]), acc[2 * t + 1]);
    }
  }

  // fold the two row-halves (lanes sub and sub^2 hold the same 8 channels)
#pragma unroll
  for (int i = 0; i < 8; ++i) acc[i] += __shfl_xor(acc[i], 2);

  // lane (rowhalf,chunk): store 4 of the 8 summed channels
  int ch = chunk * 8 + rowhalf * 4;
  float* op = out + ((size_t)(n * C_ + g * GC_ + ch)) * HW_ + p;
#pragma unroll
  for (int r = 0; r < 4; ++r) op[r * HW_] = acc[rowhalf * 4 + r];
}

// ---------------------------------------------------------------------------
extern "C" void kernel_launch(void* const* d_in, const int* in_sizes, int n_in,
                              void* d_out, int out_size, void* d_ws, size_t ws_size,
                              hipStream_t stream) {
  const float* x    = (const float*)d_in[0];
  const float* dw_w = (const float*)d_in[1];
  const float* dw_b = (const float*)d_in[2];
  const float* gn_w = (const float*)d_in[3];
  const float* gn_b = (const float*)d_in[4];
  const float* om_w = (const float*)d_in[5];
  const float* om_b = (const float*)d_in[6];
  float* out = (float*)d_out;

  // workspace layout (~71 MB)
  unsigned short* xgb = (unsigned short*)d_ws;                       // 9437184 us
  unsigned short* x1b = xgb + (size_t)N_ * CHW_;                     // 9437184 us
  unsigned int* om2 = (unsigned int*)(x1b + (size_t)N_ * CHW_);      // 8*112*9216 u32
  float* stats = (float*)(om2 + (size_t)N_ * OMROWS2_ * HW_);        // 16 f
  float2* partials = (float2*)(stats + 16);                          // 9216 float2
  unsigned short* Abf = (unsigned short*)(partials + N_ * BLKS_PER_N_);
  float* biasp = (float*)(Abf + OMP_ * C_);                          // 224 f

  k_front<<<dim3(HW_ / 32, C_ / 32, N_), dim3(32, 8), 0, stream>>>(
      x, dw_w, dw_b, xgb, x1b, partials);
  k_stats<<<N_, 256, 0, stream>>>(partials, stats);
  k_prep<<<(OMP_ * C_) / 256, 256, 0, stream>>>(om_w, om_b, Abf, biasp);
  k_gemm_mfma<<<dim3(HW_ / 128, N_), 256, 0, stream>>>(
      x1b, Abf, biasp, stats, gn_w, gn_b, om2);
  k_sample<<<9216, 256, 0, stream>>>(xgb, om2, out);
}

// Round 9
// 195.538 us; speedup vs baseline: 7.1856x; 1.0466x over previous
//
#include <hip/hip_runtime.h>

#define N_   8
#define C_   128
#define H_   96
#define W_   96
#define G_   8
#define GC_  16
#define HW_  (H_ * W_)       // 9216
#define CHW_ (C_ * HW_)      // 1179648
#define OM_  216
#define OMP_ 224             // padded: 8 groups x 28 rows (27 live + 1 pad)
#define OMROWS2_ 112         // packed dword rows per sample (224/2)
#define EPS_ 1e-5f
#define BLKS_PER_N_ 1152     // k_front blocks per sample (288*4)

typedef short bf16x8 __attribute__((ext_vector_type(8)));
typedef float f32x4 __attribute__((ext_vector_type(4)));

#if __has_builtin(__builtin_amdgcn_fdot2_f32_bf16)
#define HAVE_DOT2_ 1
typedef __bf16 bf16x2 __attribute__((ext_vector_type(2)));
static __device__ __forceinline__ bf16x2 u2bf2(unsigned int u) {
  union { unsigned int i; bf16x2 v; } c;
  c.i = u;
  return c.v;
}
#else
#define HAVE_DOT2_ 0
#endif

static __device__ __forceinline__ unsigned short f2bf(float f) {
  unsigned int u = __float_as_uint(f);
  unsigned int r = (u + 0x7fffu + ((u >> 16) & 1u)) >> 16;
  return (unsigned short)r;
}
static __device__ __forceinline__ float lo_bf(unsigned int u) {
  return __uint_as_float(u << 16);
}
static __device__ __forceinline__ float hi_bf(unsigned int u) {
  return __uint_as_float(u & 0xffff0000u);
}

// ---------------------------------------------------------------------------
// K1 (fused): single pass over x. Computes depthwise conv+bias (f32),
// emits: per-block sum/sumsq partials, conv output as bf16 NHWC (x1b,
// pre-norm), and group-planar raw x as bf16 (xgb) for the sampler.
// Grid (288, 4, 8), block (32,8): 32 px x 32 ch tile.
// ---------------------------------------------------------------------------
__global__ __launch_bounds__(256) void k_front(const float* __restrict__ x,
                                               const float* __restrict__ dw_w,
                                               const float* __restrict__ dw_b,
                                               unsigned short* __restrict__ xgb,
                                               unsigned short* __restrict__ x1b,
                                               float2* __restrict__ partials) {
  __shared__ float tile_c[32][33];   // raw center values (for xgb)
  __shared__ float tile_a[32][33];   // conv outputs (for x1b)
  __shared__ float ls[4], lq[4];
  int tx = threadIdx.x;
  int ty = threadIdx.y;
  int p0 = blockIdx.x * 32;
  int c0 = blockIdx.y * 32;
  int n = blockIdx.z;
  int p = p0 + tx;
  int h = p / W_;
  int w = p - h * W_;

  float s = 0.0f, q = 0.0f;
#pragma unroll
  for (int i = 0; i < 4; ++i) {
    int c = c0 + ty + i * 8;
    const float* wp = dw_w + c * 9;
    const float* xp = x + (n * C_ + c) * HW_;
    float acc = dw_b[c];
    float center = 0.0f;
#pragma unroll
    for (int dy = 0; dy < 3; ++dy) {
#pragma unroll
      for (int dx = 0; dx < 3; ++dx) {
        int yy = h + dy - 1;
        int xx = w + dx - 1;
        bool v = (yy >= 0) & (yy < H_) & (xx >= 0) & (xx < W_);
        float xin = v ? xp[yy * W_ + xx] : 0.0f;
        if (dy == 1 && dx == 1) center = xin;
        acc = fmaf(xin, wp[dy * 3 + dx], acc);
      }
    }
    tile_c[ty + i * 8][tx] = center;
    tile_a[ty + i * 8][tx] = acc;
    s += acc;
    q += acc * acc;
  }

  int tid = ty * 32 + tx;
#pragma unroll
  for (int o = 32; o > 0; o >>= 1) {
    s += __shfl_down(s, o);
    q += __shfl_down(q, o);
  }
  int lane = tid & 63;
  int wv = tid >> 6;
  if (lane == 0) { ls[wv] = s; lq[wv] = q; }
  __syncthreads();
  if (tid == 0) {
    int bid = blockIdx.x + 288 * blockIdx.y + BLKS_PER_N_ * n;
    partials[bid] = make_float2(ls[0] + ls[1] + ls[2] + ls[3],
                                lq[0] + lq[1] + lq[2] + lq[3]);
  }

  int c = c0 + tx;
  int g = c >> 4;
  int cc = c & 15;
#pragma unroll
  for (int i = 0; i < 4; ++i) {
    int pp = p0 + ty + i * 8;
    xgb[(((size_t)(n * G_ + g) * HW_) + pp) * GC_ + cc] = f2bf(tile_c[tx][ty + i * 8]);
    x1b[((size_t)(n * HW_) + pp) * C_ + c] = f2bf(tile_a[tx][ty + i * 8]);
  }
}

// ---------------------------------------------------------------------------
// K1b: reduce 1152 per-block partials per sample -> stats[n] = (sum, sumsq)
// ---------------------------------------------------------------------------
__global__ __launch_bounds__(256) void k_stats(const float2* __restrict__ partials,
                                               float* __restrict__ stats) {
  int n = blockIdx.x;
  int tid = threadIdx.x;
  const float2* p = partials + n * BLKS_PER_N_;
  float s = 0.0f, q = 0.0f;
  for (int i = tid; i < BLKS_PER_N_; i += 256) {
    float2 v = p[i];
    s += v.x;
    q += v.y;
  }
#pragma unroll
  for (int o = 32; o > 0; o >>= 1) {
    s += __shfl_down(s, o);
    q += __shfl_down(q, o);
  }
  __shared__ float ls[4], lq[4];
  int lane = tid & 63;
  int wv = tid >> 6;
  if (lane == 0) { ls[wv] = s; lq[wv] = q; }
  __syncthreads();
  if (tid == 0) {
    stats[n * 2 + 0] = ls[0] + ls[1] + ls[2] + ls[3];
    stats[n * 2 + 1] = lq[0] + lq[1] + lq[2] + lq[3];
  }
}

// ---------------------------------------------------------------------------
// K1c: permute+pad om_w -> A bf16 [224x128]: row o' = g*28+k holds om_w row
// g*27+k (k<27), zeros for k==27. Same permutation for bias (biasp).
// ---------------------------------------------------------------------------
__global__ __launch_bounds__(256) void k_prep(const float* __restrict__ om_w,
                                              const float* __restrict__ om_b,
                                              unsigned short* __restrict__ A,
                                              float* __restrict__ biasp) {
  int idx = blockIdx.x * 256 + threadIdx.x;   // 0 .. 224*128-1
  int o = idx >> 7;
  int cix = idx & 127;
  int g = o / 28;
  int k = o - g * 28;
  float v = (k < 27) ? om_w[(g * 27 + k) * C_ + cix] : 0.0f;
  A[idx] = f2bf(v);
  if (cix == 0) biasp[o] = (k < 27) ? om_b[g * 27 + k] : 0.0f;
}

// ---------------------------------------------------------------------------
// K4: MFMA GEMM with fused layernorm+GELU on the B operand (as R7/R8).
// Output om2 bf16-packed (2 o-rows per dword). Grid (72, 8).
// ---------------------------------------------------------------------------
__global__ __launch_bounds__(256) void k_gemm_mfma(const unsigned short* __restrict__ Bt,
                                                   const unsigned short* __restrict__ A,
                                                   const float* __restrict__ biasp,
                                                   const float* __restrict__ stats,
                                                   const float* __restrict__ gn_w,
                                                   const float* __restrict__ gn_b,
                                                   unsigned int* __restrict__ om2) {
  __shared__ unsigned short Bl[128 * 136];
  int tid = threadIdx.x;
  int pb = blockIdx.x;
  int n = blockIdx.y;
  int p0 = pb * 128;

  float sum = stats[n * 2 + 0];
  float ssq = stats[n * 2 + 1];
  const float inv = 1.0f / (float)CHW_;
  float mean = sum * inv;
  float var = ssq * inv - mean * mean;
  float rstd = rsqrtf(var + EPS_);
  int cbase = (tid & 15) * 8;
  float a8[8], b8[8];
#pragma unroll
  for (int j = 0; j < 8; ++j) {
    float gw = gn_w[cbase + j];
    float gb = gn_b[cbase + j];
    a8[j] = rstd * gw;
    b8[j] = gb - mean * rstd * gw;
  }

  const unsigned short* src = Bt + ((size_t)n * HW_ + p0) * C_;
#pragma unroll
  for (int i = 0; i < 8; ++i) {
    int idx = i * 256 + tid;
    int row = idx >> 4;
    int col = idx & 15;                 // == tid & 15
    uint4 raw = *(const uint4*)(src + row * C_ + col * 8);
    unsigned int d[4] = {raw.x, raw.y, raw.z, raw.w};
    unsigned int od[4];
#pragma unroll
    for (int t = 0; t < 4; ++t) {
      float v0 = lo_bf(d[t]);
      float v1 = hi_bf(d[t]);
      float z0 = fmaf(v0, a8[2 * t], b8[2 * t]);
      float z1 = fmaf(v1, a8[2 * t + 1], b8[2 * t + 1]);
      float g0 = 0.5f * z0 * (1.0f + erff(z0 * 0.70710678118654752f));
      float g1 = 0.5f * z1 * (1.0f + erff(z1 * 0.70710678118654752f));
      od[t] = (unsigned int)f2bf(g0) | ((unsigned int)f2bf(g1) << 16);
    }
    uint4 packed = {od[0], od[1], od[2], od[3]};
    *(uint4*)(&Bl[row * 136 + col * 8]) = packed;
  }
  __syncthreads();

  int wave = tid >> 6;
  int lane = tid & 63;
  int quad = lane >> 4;
  int l16 = lane & 15;
  int pw = wave * 32;

  bf16x8 bfrag[2][4];
#pragma unroll
  for (int st = 0; st < 2; ++st) {
    int prow = pw + st * 16 + l16;
#pragma unroll
    for (int kk = 0; kk < 4; ++kk)
      bfrag[st][kk] = *(const bf16x8*)(&Bl[prow * 136 + kk * 32 + quad * 8]);
  }

  for (int ot = 0; ot < 14; ++ot) {
    const unsigned short* Ap = A + (ot * 16 + l16) * C_ + quad * 8;
    bf16x8 afrag[4];
#pragma unroll
    for (int kk = 0; kk < 4; ++kk)
      afrag[kk] = *(const bf16x8*)(Ap + kk * 32);

    f32x4 acc[2] = {{0.f, 0.f, 0.f, 0.f}, {0.f, 0.f, 0.f, 0.f}};
#pragma unroll
    for (int st = 0; st < 2; ++st)
#pragma unroll
      for (int kk = 0; kk < 4; ++kk)
        acc[st] = __builtin_amdgcn_mfma_f32_16x16x32_bf16(afrag[kk], bfrag[st][kk], acc[st], 0, 0, 0);

    int o0 = ot * 16 + quad * 4;               // even
    float4 bv = *(const float4*)(biasp + o0);
#pragma unroll
    for (int st = 0; st < 2; ++st) {
      int p = p0 + pw + st * 16 + l16;
      unsigned int pk0 = (unsigned int)f2bf(acc[st][0] + bv.x) |
                         ((unsigned int)f2bf(acc[st][1] + bv.y) << 16);
      unsigned int pk1 = (unsigned int)f2bf(acc[st][2] + bv.z) |
                         ((unsigned int)f2bf(acc[st][3] + bv.w) << 16);
      unsigned int* Cp = om2 + ((size_t)n * OMROWS2_ + (o0 >> 1)) * HW_ + p;
      Cp[0] = pk0;
      Cp[HW_] = pk1;
    }
  }
}

// ---------------------------------------------------------------------------
// K5: deformable bilinear sampling from bf16 group-planar xgb.
// Phase 1 (576 jobs): redistribute 4 corner weights onto physical rows
// xs/xs+1, pack the two (y0,y1)-weights per x-row as a bf16 pair, and emit
// one int4 {pk_xrow0, pk_xrow1, off_y0, off_y1} per (pt,px).
// Phase 2: 4 lanes/px; per pt: 1 ds_read_b128 + 2 global dwordx4 +
// 8 v_perm + 8 v_dot2_f32_bf16 (pair = (v_y0, v_y1)). __shfl_xor(2) folds
// the two x-rows. Grid: 9216 blocks = 8n x 8g x 144 p-blocks.
// ---------------------------------------------------------------------------
__global__ __launch_bounds__(256) void k_sample(const unsigned short* __restrict__ xgb,
                                                const unsigned int* __restrict__ om2,
                                                float* __restrict__ out) {
  __shared__ int4 s_wa[9 * 64];   // {pk0, pk1, off_y0, off_y1}

  int tid = threadIdx.x;
  int ord = blockIdx.x;
  int n = ord & 7;
  int t2 = ord >> 3;
  int g = t2 & 7;
  int pb = t2 >> 3;
  int p0 = pb * 64;

  const unsigned int* omb = om2 + ((size_t)n * OMROWS2_ + g * 14) * HW_ + p0;
  for (int j = tid; j < 576; j += 256) {
    int pt = j >> 6;
    int px = j & 63;
    int p = p0 + px;
    int h = p / W_;
    int w = p - h * W_;
    unsigned int od = omb[pt * HW_ + px];
    float offx = lo_bf(od);
    float offy = hi_bf(od);
    unsigned int md = omb[(9 + (pt >> 1)) * HW_ + px];
    float m = (pt & 1) ? hi_bf(md) : lo_bf(md);
    float locy = (float)(h + pt / 3 - 1) + offy;
    float locx = (float)(w + pt % 3 - 1) + offx;
    float y0f = floorf(locy);
    float x0f = floorf(locx);
    float ly = locy - y0f;
    float lx = locx - x0f;
    int y0 = (int)y0f;
    int x0 = (int)x0f;
    int y1 = y0 + 1;
    int x1 = x0 + 1;
    bool vy0 = (y0 >= 0) & (y0 < H_);
    bool vy1 = (y1 >= 0) & (y1 < H_);
    bool vx0 = (x0 >= 0) & (x0 < W_);
    bool vx1 = (x1 >= 0) & (x1 < W_);
    float t0 = (1.0f - ly) * m;
    float t1 = ly * m;
    float u0 = 1.0f - lx;
    float w00 = (vy0 & vx0) ? t0 * u0 : 0.0f;
    float w01 = (vy0 & vx1) ? t0 * lx : 0.0f;
    float w10 = (vy1 & vx0) ? t1 * u0 : 0.0f;
    float w11 = (vy1 & vx1) ? t1 * lx : 0.0f;
    int yc0 = min(max(y0, 0), H_ - 1);
    int yc1 = min(max(y1, 0), H_ - 1);
    int xs  = min(max(x0, 0), W_ - 2);
    int idx0 = min(max(x0, 0), W_ - 1) - xs;       // 0 or 1
    int idx1 = min(max(x1, 0), W_ - 1) - xs;       // 0 or 1
    // row-weights: x-row0 = (y0: wr0y0, y1: wr0y1), x-row1 likewise
    float wr0y0 = (idx0 == 0 ? w00 : 0.0f) + (idx1 == 0 ? w01 : 0.0f);
    float wr1y0 = (idx0 == 1 ? w00 : 0.0f) + (idx1 == 1 ? w01 : 0.0f);
    float wr0y1 = (idx0 == 0 ? w10 : 0.0f) + (idx1 == 0 ? w11 : 0.0f);
    float wr1y1 = (idx0 == 1 ? w10 : 0.0f) + (idx1 == 1 ? w11 : 0.0f);
    int4 wa;
    wa.x = (int)((unsigned int)f2bf(wr0y0) | ((unsigned int)f2bf(wr0y1) << 16));
    wa.y = (int)((unsigned int)f2bf(wr1y0) | ((unsigned int)f2bf(wr1y1) << 16));
    wa.z = (yc0 * W_ + xs) * GC_;
    wa.w = (yc1 * W_ + xs) * GC_;
    s_wa[j] = wa;
  }
  __syncthreads();

  int px_l = tid >> 2;             // 0..63
  int sub = tid & 3;               // x-row = sub>>1, channel-chunk = sub&1
  int rowhalf = sub >> 1;
  int chunk = sub & 1;
  int p = p0 + px_l;
  const unsigned short* xbb = xgb + ((size_t)(n * G_ + g) * HW_) * GC_;

  float acc[8] = {0, 0, 0, 0, 0, 0, 0, 0};
#pragma unroll
  for (int pt = 0; pt < 9; ++pt) {
    int4 wa = s_wa[pt * 64 + px_l];
    unsigned int aw = (unsigned int)(rowhalf ? wa.y : wa.x);  // (w_y0, w_y1) bf16x2
    uint4 r0 = *(const uint4*)(xbb + wa.z + sub * 8);         // y0 row-pair
    uint4 r1 = *(const uint4*)(xbb + wa.w + sub * 8);         // y1 row-pair
    unsigned int d0[4] = {r0.x, r0.y, r0.z, r0.w};
    unsigned int d1[4] = {r1.x, r1.y, r1.z, r1.w};
#if HAVE_DOT2_
    bf16x2 a2 = u2bf2(aw);
#pragma unroll
    for (int t = 0; t < 4; ++t) {
      unsigned int blo = __builtin_amdgcn_perm(d1[t], d0[t], 0x05040100u); // (v0.lo, v1.lo)
      unsigned int bhi = __builtin_amdgcn_perm(d1[t], d0[t], 0x07060302u); // (v0.hi, v1.hi)
      acc[2 * t]     = __builtin_amdgcn_fdot2_f32_bf16(a2, u2bf2(blo), acc[2 * t], false);
      acc[2 * t + 1] = __builtin_amdgcn_fdot2_f32_bf16(a2, u2bf2(bhi), acc[2 * t + 1], false);
    }
#else
    float w0 = lo_bf(aw);
    float w1 = hi_bf(aw);
#pragma unroll
    for (int t = 0; t < 4; ++t) {
      acc[2 * t]     = fmaf(w0, lo_bf(d0[t]), acc[2 * t]);
      acc[2 * t + 1] = fmaf(w0, hi_bf(d0[t]), acc[2 * t + 1]);
      acc[2 * t]     = fmaf(w1, lo_bf(d1[t]), acc[2 * t]);
      acc[2 * t + 1] = fmaf(w1, hi_bf(d1[t]), acc[2 * t + 1]);
    }
#endif
  }

  // fold the two x-rows (lanes sub and sub^2 hold the same 8 channels)
#pragma unroll
  for (int i = 0; i < 8; ++i) acc[i] += __shfl_xor(acc[i], 2);

  int ch = chunk * 8 + rowhalf * 4;
  float* op = out + ((size_t)(n * C_ + g * GC_ + ch)) * HW_ + p;
#pragma unroll
  for (int r = 0; r < 4; ++r) op[r * HW_] = acc[rowhalf * 4 + r];
}

// ---------------------------------------------------------------------------
extern "C" void kernel_launch(void* const* d_in, const int* in_sizes, int n_in,
                              void* d_out, int out_size, void* d_ws, size_t ws_size,
                              hipStream_t stream) {
  const float* x    = (const float*)d_in[0];
  const float* dw_w = (const float*)d_in[1];
  const float* dw_b = (const float*)d_in[2];
  const float* gn_w = (const float*)d_in[3];
  const float* gn_b = (const float*)d_in[4];
  const float* om_w = (const float*)d_in[5];
  const float* om_b = (const float*)d_in[6];
  float* out = (float*)d_out;

  // workspace layout (~71 MB)
  unsigned short* xgb = (unsigned short*)d_ws;                       // 9437184 us
  unsigned short* x1b = xgb + (size_t)N_ * CHW_;                     // 9437184 us
  unsigned int* om2 = (unsigned int*)(x1b + (size_t)N_ * CHW_);      // 8*112*9216 u32
  float* stats = (float*)(om2 + (size_t)N_ * OMROWS2_ * HW_);        // 16 f
  float2* partials = (float2*)(stats + 16);                          // 9216 float2
  unsigned short* Abf = (unsigned short*)(partials + N_ * BLKS_PER_N_);
  float* biasp = (float*)(Abf + OMP_ * C_);                          // 224 f

  k_front<<<dim3(HW_ / 32, C_ / 32, N_), dim3(32, 8), 0, stream>>>(
      x, dw_w, dw_b, xgb, x1b, partials);
  k_stats<<<N_, 256, 0, stream>>>(partials, stats);
  k_prep<<<(OMP_ * C_) / 256, 256, 0, stream>>>(om_w, om_b, Abf, biasp);
  k_gemm_mfma<<<dim3(HW_ / 128, N_), 256, 0, stream>>>(
      x1b, Abf, biasp, stats, gn_w, gn_b, om2);
  k_sample<<<9216, 256, 0, stream>>>(xgb, om2, out);
}